// Round 4
// baseline (2055.616 us; speedup 1.0000x reference)
//
#include <hip/hip_runtime.h>
#include <hip/hip_bf16.h>
#include <math.h>

#define BB 64
#define SS 512
#define HH 64
#define DD 128
#define NHD 8
#define ROWS (BB*SS)   // 32768

typedef unsigned short u16;
typedef __attribute__((ext_vector_type(8))) short bf16x8;
typedef __attribute__((ext_vector_type(4))) float f32x4;

__device__ __forceinline__ u16 f2b(float f) {
  union { float f; unsigned u; } x; x.f = f;
  unsigned r = x.u + 0x7fffu + ((x.u >> 16) & 1u);
  return (u16)(r >> 16);
}

__device__ __forceinline__ float fast_tanh(float x) {
  float ax = fminf(fabsf(x), 15.f);
  float e = __expf(2.f * ax);
  float r = 1.f - __fdividef(2.f, e + 1.f);
  return copysignf(r, x);
}

// register-broadcast: read lane `l` of v (l compile-time) -> wave-uniform
__device__ __forceinline__ float rl(float v, int l) {
  return __uint_as_float(__builtin_amdgcn_readlane(__float_as_uint(v), l));
}

// ---------------------------------------------------------------------------
// SDE scan: one block per batch, 4 waves, 2 barriers/step.
// All cross-lane broadcasts via v_readlane (VALU) instead of LDS reads —
// the LDS pipe (shared by 4 waves) was the round-2/3 bottleneck.
// y is register-resident in every wave (stage C redundant in all waves).
// Wave roles: stage A: w0,w1 -> h1 cols 0-63/64-127; w2,w3 -> g1.
//             stage B: w0,w1 -> h2 (redundant); w2,w3 -> gc (redundant).
//             stage C: all waves full (redundant).
// ---------------------------------------------------------------------------
__global__ __launch_bounds__(256, 1) void sde_kernel(
    const float* __restrict__ ts, const float* __restrict__ noise,
    const float* __restrict__ dW1, const float* __restrict__ db1,
    const float* __restrict__ dW2, const float* __restrict__ db2,
    const float* __restrict__ dW3, const float* __restrict__ db3,
    const float* __restrict__ gW1, const float* __restrict__ gb1,
    const float* __restrict__ gW2, const float* __restrict__ gb2,
    const float* __restrict__ pmind, const float* __restrict__ pmaxd,
    float* __restrict__ out) {
  const int b = blockIdx.x, t = threadIdx.x;
  const int w = t >> 6, lane = t & 63;
  __shared__ float h1g1[256];           // h1[0..127], g1[128..255]
  __shared__ float h2s[64], gcs[64];
  __shared__ float tl_s[512], hs_s[512], sq_s[512];

  const float mind = fabsf(pmind[0]);
  const float maxd = fabsf(pmaxd[0]);

  // ---- stage-A weights: one layer-1 output column per lane ----
  const int colA = (w & 1) * 64 + lane;
  const float* W1 = (w < 2) ? dW1 : gW1;
  float wA[64];
#pragma unroll
  for (int k = 0; k < 64; k++) wA[k] = W1[k * 128 + colA];
  const float wAt = W1[64 * 128 + colA];
  const float bA = ((w < 2) ? db1 : gb1)[colA];

  // ---- stage-B weights: col = lane; drift (w0,w1) or gate (w2,w3) ----
  const float* W2 = (w < 2) ? dW2 : gW2;
  float wB[128];
#pragma unroll
  for (int k = 0; k < 128; k++) wB[k] = W2[k * 64 + lane];
  const float bB = ((w < 2) ? db2 : gb2)[lane];

  // ---- stage-C weights: col = lane, replicated in every wave ----
  float wC[64];
#pragma unroll
  for (int k = 0; k < 64; k++) wC[k] = dW3[k * 64 + lane];
  const float bC = db3[lane];

  // ---- prologue ----
  for (int i = t; i < 512; i += 256) tl_s[i] = ts[i * 3];
  __syncthreads();
  for (int i = t; i < 511; i += 256) {
    float hh = tl_s[i + 1] - tl_s[i];
    hs_s[i] = hh;
    sq_s[i] = sqrtf(hh);
  }
  float y = 0.1f;
  if (lane < 3) y = fminf(fmaxf(ts[b * 1536 + lane], 0.01f), 10.f);
  if (w == 0) out[(long)b * 32768 + lane] = y;
  float nz = noise[b * 64 + lane];
  __syncthreads();

  for (int i = 0; i < 511; i++) {
    float nzn = 0.f;
    if (i < 510) nzn = noise[(long)(i + 1) * 4096 + b * 64 + lane];
    const float tl = tl_s[i];

    // ---- stage A: layer 1 via readlane broadcast of in-register y ----
    float a0 = 0.f, a1 = 0.f, a2 = 0.f, a3 = 0.f;
#pragma unroll
    for (int k = 0; k < 64; k += 4) {
      a0 += rl(y, k + 0) * wA[k + 0];
      a1 += rl(y, k + 1) * wA[k + 1];
      a2 += rl(y, k + 2) * wA[k + 2];
      a3 += rl(y, k + 3) * wA[k + 3];
    }
    float acc1 = (a0 + a1) + (a2 + a3) + tl * wAt + bA;
    h1g1[((w < 2) ? 0 : 128) + colA] = fast_tanh(acc1);
    __syncthreads();                       // barrier 1

    // ---- stage B: bulk LDS pull (1 ds_read_b64/wave) + readlane ----
    float2 hr = *(const float2*)&h1g1[((w < 2) ? 0 : 128) + 2 * lane];
    float c0 = 0.f, c1 = 0.f, c2 = 0.f, c3 = 0.f;
#pragma unroll
    for (int k = 0; k < 128; k += 4) {
      c0 += rl(hr.x, (k >> 1) + 0) * wB[k + 0];
      c1 += rl(hr.y, (k >> 1) + 0) * wB[k + 1];
      c2 += rl(hr.x, (k >> 1) + 1) * wB[k + 2];
      c3 += rl(hr.y, (k >> 1) + 1) * wB[k + 3];
    }
    float p = (c0 + c1) + (c2 + c3) + bB;
    if (w < 2) {
      if (w == 0) h2s[lane] = fast_tanh(p);
    } else {
      float gcv = fmaxf(p, 0.f) + __logf(1.f + __expf(-fabsf(p))) + mind;
      if (w == 2) gcs[lane] = gcv;
    }
    __syncthreads();                       // barrier 2

    // ---- stage C: per-lane pulls + readlane, redundant in every wave ----
    float h2l = h2s[lane];
    float gcl = gcs[lane];
    float d0 = 0.f, d1 = 0.f, d2 = 0.f, d3 = 0.f;
#pragma unroll
    for (int k = 0; k < 64; k += 4) {
      d0 += rl(h2l, k + 0) * wC[k + 0];
      d1 += rl(h2l, k + 1) * wC[k + 1];
      d2 += rl(h2l, k + 2) * wC[k + 2];
      d3 += rl(h2l, k + 3) * wC[k + 3];
    }
    float s3 = (d0 + d1) + (d2 + d3);
    float dc = fminf(fmaxf(s3 + bC, -maxd), maxd);
    float gg = gcl * fminf(fmaxf(y, -10.f), 10.f);
    float yn = y + dc * y * hs_s[i] + gg * nz * sq_s[i];
    yn = fminf(fmaxf(yn, 0.01f), 10.f);
    y = yn;
    if (w == 0) out[(long)b * 32768 + (i + 1) * 64 + lane] = yn;
    nz = nzn;
    // no third barrier: next stage-A writes h1g1 (readers finished before
    // barrier 2); h2s/gcs next written after next barrier 1.
  }
}

// ---------------------------------------------------------------------------
// Weight prep: cast fp32 -> bf16 and transpose [K][N] -> [N][K].
// QKV packed contiguously per layer: [layer][ q(128x128) k v ] for fused GEMM.
// ---------------------------------------------------------------------------
__global__ __launch_bounds__(256) void prep_weights(
    const float* __restrict__ in_W, const float* __restrict__ Wq,
    const float* __restrict__ Wk, const float* __restrict__ Wv,
    const float* __restrict__ Wo, const float* __restrict__ fW1,
    const float* __restrict__ fW2,
    u16* __restrict__ inWt, u16* __restrict__ qkvWt, u16* __restrict__ Wot,
    u16* __restrict__ fW1t, u16* __restrict__ fW2t) {
  const int z = blockIdx.z, layer = blockIdx.y, tile = blockIdx.x;
  const float* src; u16* dst; int R, C, nl;
  switch (z) {
    case 0: src = in_W; dst = inWt; R = 64; C = 128; nl = 1; break;
    case 1: src = Wq + layer * 16384; dst = qkvWt + layer * 49152; R = 128; C = 128; nl = 4; break;
    case 2: src = Wk + layer * 16384; dst = qkvWt + layer * 49152 + 16384; R = 128; C = 128; nl = 4; break;
    case 3: src = Wv + layer * 16384; dst = qkvWt + layer * 49152 + 32768; R = 128; C = 128; nl = 4; break;
    case 4: src = Wo + layer * 16384; dst = Wot + layer * 16384; R = 128; C = 128; nl = 4; break;
    case 5: src = fW1 + layer * 65536; dst = fW1t + layer * 65536; R = 128; C = 512; nl = 4; break;
    default: src = fW2 + layer * 65536; dst = fW2t + layer * 65536; R = 512; C = 128; nl = 4; break;
  }
  const int nt = (R / 32) * (C / 32);
  if (layer >= nl || tile >= nt) return;
  const int tpr = C / 32;
  const int r0 = (tile / tpr) * 32, c0 = (tile % tpr) * 32;
  __shared__ float tl[32][33];
  const int tx = threadIdx.x & 31, ty = threadIdx.x >> 5;
#pragma unroll
  for (int p = 0; p < 4; p++)
    tl[ty + 8 * p][tx] = src[(long)(r0 + ty + 8 * p) * C + c0 + tx];
  __syncthreads();
#pragma unroll
  for (int p = 0; p < 4; p++)
    dst[(long)(c0 + ty + 8 * p) * R + r0 + tx] = f2b(tl[tx][ty + 8 * p]);
}

// combined qkv bias [4][384]
__global__ __launch_bounds__(384) void prep_bias(
    const float* __restrict__ bq, const float* __restrict__ bk,
    const float* __restrict__ bv, float* __restrict__ bqkv) {
  const int l = blockIdx.x, c = threadIdx.x;
  float v;
  if (c < 128) v = bq[l * 128 + c];
  else if (c < 256) v = bk[l * 128 + c - 128];
  else v = bv[l * 128 + c - 256];
  bqkv[l * 384 + c] = v;
}

// ---------------------------------------------------------------------------
__global__ __launch_bounds__(256) void cast_kernel(const float* __restrict__ src,
                                                   u16* __restrict__ dst) {
  const long base = ((long)blockIdx.x * 256 + threadIdx.x) * 8;
  float4 a = *(const float4*)&src[base];
  float4 b = *(const float4*)&src[base + 4];
  ushort4 o0, o1;
  o0.x = f2b(a.x); o0.y = f2b(a.y); o0.z = f2b(a.z); o0.w = f2b(a.w);
  o1.x = f2b(b.x); o1.y = f2b(b.y); o1.z = f2b(b.z); o1.w = f2b(b.w);
  *(ushort4*)&dst[base] = o0;
  *(ushort4*)&dst[base + 4] = o1;
}

// ---------------------------------------------------------------------------
// bf16 MFMA GEMM: C[M,N] = A[M,K] @ Bt[N,K]^T + bias.
// MODE 0: fp32 out. MODE 1: bf16 out + relu. MODE 2: fp32+bf16. MODE 3: bf16.
// ---------------------------------------------------------------------------
template <int MODE>
__global__ __launch_bounds__(256) void mfma_gemm(
    const u16* __restrict__ A, const u16* __restrict__ Bt,
    const float* __restrict__ bias, float* __restrict__ outF,
    u16* __restrict__ outB, int K, int N) {
  __shared__ u16 As[128 * 40];
  __shared__ u16 Bs[64 * 40];
  const int t = threadIdx.x;
  const int nb = blockIdx.x * 64;
  const long mb = (long)blockIdx.y * 128;
  const int lane = t & 63, wave = t >> 6;
  const int wm = (wave >> 1) * 64, wn = (wave & 1) * 32;
  const int fr = lane & 15, quad = lane >> 4;

  f32x4 zero = {0.f, 0.f, 0.f, 0.f};
  f32x4 acc[4][2];
#pragma unroll
  for (int mi = 0; mi < 4; mi++)
#pragma unroll
    for (int ni = 0; ni < 2; ni++) acc[mi][ni] = zero;

  for (int k0 = 0; k0 < K; k0 += 32) {
#pragma unroll
    for (int p = 0; p < 2; p++) {
      int idx = t + p * 256, row = idx >> 2, seg = idx & 3;
      int4 v = *(const int4*)&A[(mb + row) * K + k0 + seg * 8];
      *(int4*)&As[row * 40 + seg * 8] = v;
    }
    {
      int row = t >> 2, seg = t & 3;
      int4 v = *(const int4*)&Bt[(long)(nb + row) * K + k0 + seg * 8];
      *(int4*)&Bs[row * 40 + seg * 8] = v;
    }
    __syncthreads();
    bf16x8 af[4], bfr[2];
#pragma unroll
    for (int mi = 0; mi < 4; mi++)
      af[mi] = *(const bf16x8*)&As[(wm + mi * 16 + fr) * 40 + quad * 8];
#pragma unroll
    for (int ni = 0; ni < 2; ni++)
      bfr[ni] = *(const bf16x8*)&Bs[(wn + ni * 16 + fr) * 40 + quad * 8];
#pragma unroll
    for (int mi = 0; mi < 4; mi++)
#pragma unroll
      for (int ni = 0; ni < 2; ni++)
        acc[mi][ni] = __builtin_amdgcn_mfma_f32_16x16x32_bf16(
            af[mi], bfr[ni], acc[mi][ni], 0, 0, 0);
    __syncthreads();
  }

#pragma unroll
  for (int mi = 0; mi < 4; mi++)
#pragma unroll
    for (int ni = 0; ni < 2; ni++) {
      int col = nb + wn + ni * 16 + fr;
      float bv = bias[col];
#pragma unroll
      for (int r = 0; r < 4; r++) {
        long row = mb + wm + mi * 16 + quad * 4 + r;
        float v = acc[mi][ni][r] + bv;
        if (MODE == 0) {
          outF[row * N + col] = v;
        } else if (MODE == 1) {
          outB[row * N + col] = f2b(fmaxf(v, 0.f));
        } else if (MODE == 2) {
          outF[row * N + col] = v;
          outB[row * N + col] = f2b(v);
        } else {
          outB[row * N + col] = f2b(v);
        }
      }
    }
}

// ---------------------------------------------------------------------------
// Flash attention, bf16 MFMA, dh=16. Input is packed QKV [row][384]
// (Q at +0, K at +128, V at +256). One block per (b,h).
// ---------------------------------------------------------------------------
__global__ __launch_bounds__(256, 2) void attn_mfma(
    const u16* __restrict__ QKV, u16* __restrict__ Og) {
  const int bh = blockIdx.x;
  const int b = bh >> 3, h = bh & 7;
  __shared__ u16 Ks[512 * 24];
  __shared__ u16 Vt[16 * 520];
  __shared__ u16 Pb[4][16 * 40];
  const int t = threadIdx.x;
  const int w = t >> 6, lane = t & 63;
  const int m = lane & 15, quad = lane >> 4;
  const long qbase = ((long)b * SS) * 384 + h * 16;
  const long obase = ((long)b * SS) * DD + h * 16;

  for (int i = t; i < 1024; i += 256) {
    int row = i >> 1, half = i & 1;
    *(int4*)&Ks[row * 24 + half * 8] =
        *(const int4*)&QKV[qbase + 128 + (long)row * 384 + half * 8];
    u16 v8[8];
    *(int4*)v8 = *(const int4*)&QKV[qbase + 256 + (long)row * 384 + half * 8];
#pragma unroll
    for (int jj = 0; jj < 8; jj++) Vt[(half * 8 + jj) * 520 + row] = v8[jj];
  }
  __syncthreads();

  const float scale = 0.25f;   // 1/sqrt(16)
  for (int qt = w; qt < 32; qt += 4) {
    const int q0 = qt * 16;
    bf16x8 qf = {0, 0, 0, 0, 0, 0, 0, 0};
    if (quad < 2)
      qf = *(const bf16x8*)&QKV[qbase + (long)(q0 + m) * 384 + quad * 8];
    f32x4 oacc = {0.f, 0.f, 0.f, 0.f};
    float mrun[4] = {-1e30f, -1e30f, -1e30f, -1e30f};
    float lrun[4] = {0.f, 0.f, 0.f, 0.f};

    for (int kt = 0; kt < 16; kt++) {
      const int k0 = kt * 32;
      bf16x8 kf0 = {0, 0, 0, 0, 0, 0, 0, 0};
      bf16x8 kf1 = {0, 0, 0, 0, 0, 0, 0, 0};
      if (quad < 2) {
        kf0 = *(const bf16x8*)&Ks[(k0 + m) * 24 + quad * 8];
        kf1 = *(const bf16x8*)&Ks[(k0 + 16 + m) * 24 + quad * 8];
      }
      f32x4 z4 = {0.f, 0.f, 0.f, 0.f};
      f32x4 slo = __builtin_amdgcn_mfma_f32_16x16x32_bf16(qf, kf0, z4, 0, 0, 0);
      f32x4 shi = __builtin_amdgcn_mfma_f32_16x16x32_bf16(qf, kf1, z4, 0, 0, 0);
      u16* pb = &Pb[w][0];
#pragma unroll
      for (int r = 0; r < 4; r++) {
        float sl = slo[r] * scale, sh = shi[r] * scale;
        float mx = fmaxf(sl, sh);
        mx = fmaxf(mx, __shfl_xor(mx, 1));
        mx = fmaxf(mx, __shfl_xor(mx, 2));
        mx = fmaxf(mx, __shfl_xor(mx, 4));
        mx = fmaxf(mx, __shfl_xor(mx, 8));
        float nm = fmaxf(mrun[r], mx);
        float alpha = __expf(mrun[r] - nm);
        mrun[r] = nm;
        float pl = __expf(sl - nm), ph = __expf(sh - nm);
        float rs = pl + ph;
        rs += __shfl_xor(rs, 1);
        rs += __shfl_xor(rs, 2);
        rs += __shfl_xor(rs, 4);
        rs += __shfl_xor(rs, 8);
        lrun[r] = lrun[r] * alpha + rs;
        oacc[r] *= alpha;
        int prow = quad * 4 + r;
        pb[prow * 40 + m] = f2b(pl);
        pb[prow * 40 + 16 + m] = f2b(ph);
      }
      __builtin_amdgcn_s_waitcnt(0xC07F);   // lgkmcnt(0)
      bf16x8 pf = *(const bf16x8*)&pb[m * 40 + quad * 8];
      bf16x8 vf = *(const bf16x8*)&Vt[m * 520 + k0 + quad * 8];
      oacc = __builtin_amdgcn_mfma_f32_16x16x32_bf16(pf, vf, oacc, 0, 0, 0);
    }

#pragma unroll
    for (int r = 0; r < 4; r++) {
      float inv = __fdividef(1.f, lrun[r]);
      Og[obase + (long)(q0 + quad * 4 + r) * DD + m] = f2b(oacc[r] * inv);
    }
  }
}

// ---------------------------------------------------------------------------
__global__ __launch_bounds__(256) void ln_add_kernel(
    const float* __restrict__ X, const float* __restrict__ R,
    const float* __restrict__ gamma, const float* __restrict__ beta,
    float* __restrict__ Out, u16* __restrict__ OutB) {
  const int t = threadIdx.x;
  const int wave = t >> 6, lane = t & 63;
  const long row = (long)blockIdx.x * 4 + wave;
  const long off = row * DD + lane * 2;
  float2 xv = *(const float2*)&X[off];
  float2 rv = *(const float2*)&R[off];
  float a0 = xv.x + rv.x, a1 = xv.y + rv.y;
  float s = a0 + a1, ss = a0 * a0 + a1 * a1;
#pragma unroll
  for (int o = 1; o < 64; o <<= 1) {
    s += __shfl_xor(s, o);
    ss += __shfl_xor(ss, o);
  }
  float mean = s * (1.f / 128.f);
  float var = ss * (1.f / 128.f) - mean * mean;
  float rstd = rsqrtf(var + 1e-5f);
  float2 o;
  o.x = (a0 - mean) * rstd * gamma[lane * 2] + beta[lane * 2];
  o.y = (a1 - mean) * rstd * gamma[lane * 2 + 1] + beta[lane * 2 + 1];
  *(float2*)&Out[off] = o;
  ushort2 ob; ob.x = f2b(o.x); ob.y = f2b(o.y);
  *(ushort2*)&OutB[off] = ob;
}

// ---------------------------------------------------------------------------
__global__ __launch_bounds__(128) void pool_kernel(const float* __restrict__ X,
                                                   float* __restrict__ P) {
  const int b = blockIdx.x, c = threadIdx.x;
  float acc = 0.f;
  for (int s = 0; s < SS; s++) acc += X[((long)b * SS + s) * DD + c];
  P[b * DD + c] = acc * (1.f / 512.f);
}

__global__ __launch_bounds__(64) void cls_kernel(
    const float* __restrict__ P, const float* __restrict__ W1,
    const float* __restrict__ b1, const float* __restrict__ W2,
    const float* __restrict__ b2, float* __restrict__ L) {
  const int b = blockIdx.x, t = threadIdx.x;
  __shared__ float sp[128];
  __shared__ float sh[64];
  sp[t] = P[b * DD + t];
  sp[t + 64] = P[b * DD + 64 + t];
  __syncthreads();
  float acc = b1[t];
  for (int k = 0; k < 128; k++) acc += sp[k] * W1[k * 64 + t];
  sh[t] = fmaxf(acc, 0.f);
  __syncthreads();
  if (t < 5) {
    float acc2 = b2[t];
    for (int k = 0; k < 64; k++) acc2 += sh[k] * W2[k * 5 + t];
    L[b * 5 + t] = acc2;
  }
}

// ---------------------------------------------------------------------------
extern "C" void kernel_launch(void* const* d_in, const int* in_sizes, int n_in,
                              void* d_out, int out_size, void* d_ws, size_t ws_size,
                              hipStream_t stream) {
  const float* ts    = (const float*)d_in[0];
  const float* noise = (const float*)d_in[2];
  const float* dW1   = (const float*)d_in[3];
  const float* db1   = (const float*)d_in[4];
  const float* dW2   = (const float*)d_in[5];
  const float* db2   = (const float*)d_in[6];
  const float* dW3   = (const float*)d_in[7];
  const float* db3   = (const float*)d_in[8];
  const float* gW1   = (const float*)d_in[9];
  const float* gb1   = (const float*)d_in[10];
  const float* gW2   = (const float*)d_in[11];
  const float* gb2   = (const float*)d_in[12];
  const float* mind  = (const float*)d_in[13];
  const float* maxd  = (const float*)d_in[14];
  const float* in_W  = (const float*)d_in[15];
  const float* in_b  = (const float*)d_in[16];
  const float* Wq    = (const float*)d_in[17];
  const float* bq    = (const float*)d_in[18];
  const float* Wk    = (const float*)d_in[19];
  const float* bk    = (const float*)d_in[20];
  const float* Wv    = (const float*)d_in[21];
  const float* bv    = (const float*)d_in[22];
  const float* Wo    = (const float*)d_in[23];
  const float* bo    = (const float*)d_in[24];
  const float* ln1s  = (const float*)d_in[25];
  const float* ln1b  = (const float*)d_in[26];
  const float* fW1   = (const float*)d_in[27];
  const float* fb1   = (const float*)d_in[28];
  const float* fW2   = (const float*)d_in[29];
  const float* fb2   = (const float*)d_in[30];
  const float* ln2s  = (const float*)d_in[31];
  const float* ln2b  = (const float*)d_in[32];
  const float* cW1   = (const float*)d_in[33];
  const float* cb1   = (const float*)d_in[34];
  const float* cW2   = (const float*)d_in[35];
  const float* cb2   = (const float*)d_in[36];

  float* logits = (float*)d_out;
  float* sde    = logits + BB * 5;

  // Workspace layout (<= ~86 MB):
  char* W = (char*)d_ws;
  float* bx    = (float*)(W);                 // 16 MB fp32 x
  u16*  bxb    = (u16*)(W + (16u << 20));     //  8 MB bf16 x
  u16*  bqkvb  = (u16*)(W + (24u << 20));     // 25.2 MB bf16 packed QKV [row][384]
  u16*  bh     = (u16*)(W + (24u << 20));     // 32 MB bf16 FFN hidden (alias, post-attn)
  u16*  bob    = (u16*)(W + (56u << 20));     //  8 MB bf16 attn out
  float* bqf   = (float*)(W + (64u << 20));   // 16 MB fp32 (O-proj / FFN2 out)
  u16*  bsb    = (u16*)(W + (80u << 20));     //  4 MB bf16 sde feats
  u16*  wts    = (u16*)(W + (84u << 20));     // ~1.5 MB bf16 weights
  float* bqkv_bias = (float*)(W + (86u << 20));  // 6 KB
  float* bp    = bqkv_bias + 4 * 384;         // pooled 64x128

  u16* inWt  = wts;                 // [128][64]
  u16* qkvWt = inWt + 8192;         // [4][3][128][128]
  u16* Wot   = qkvWt + 196608;      // [4][128][128]
  u16* fW1t  = Wot + 65536;         // [4][512][128]
  u16* fW2t  = fW1t + 262144;       // [4][128][512]

  prep_weights<<<dim3(64, 4, 7), 256, 0, stream>>>(in_W, Wq, Wk, Wv, Wo, fW1, fW2,
                                                   inWt, qkvWt, Wot, fW1t, fW2t);
  prep_bias<<<4, 384, 0, stream>>>(bq, bk, bv, bqkv_bias);

  sde_kernel<<<64, 256, 0, stream>>>(ts, noise, dW1, db1, dW2, db2, dW3, db3,
                                     gW1, gb1, gW2, gb2, mind, maxd, sde);

  cast_kernel<<<1024, 256, 0, stream>>>(sde, bsb);

  // x = sde @ in_W + in_b  (dual fp32+bf16 output)
  mfma_gemm<2><<<dim3(2, 256), 256, 0, stream>>>(bsb, inWt, in_b, bx, bxb, 64, 128);

  for (int l = 0; l < 4; l++) {
    // fused QKV: [32768x128] @ [128x384]
    mfma_gemm<3><<<dim3(6, 256), 256, 0, stream>>>(bxb, qkvWt + l * 49152,
                                                   bqkv_bias + l * 384, nullptr,
                                                   bqkvb, 128, 384);
    attn_mfma<<<BB * NHD, 256, 0, stream>>>(bqkvb, bob);
    mfma_gemm<0><<<dim3(2, 256), 256, 0, stream>>>(bob, Wot + l * 16384, bo + l * DD, bqf, nullptr, 128, 128);
    ln_add_kernel<<<ROWS / 4, 256, 0, stream>>>(bx, bqf, ln1s + l * DD, ln1b + l * DD, bx, bxb);
    mfma_gemm<1><<<dim3(8, 256), 256, 0, stream>>>(bxb, fW1t + l * 65536, fb1 + l * 512, nullptr, bh, 128, 512);
    mfma_gemm<0><<<dim3(2, 256), 256, 0, stream>>>(bh, fW2t + l * 65536, fb2 + l * DD, bqf, nullptr, 512, 128);
    ln_add_kernel<<<ROWS / 4, 256, 0, stream>>>(bx, bqf, ln2s + l * DD, ln2b + l * DD, bx, bxb);
  }

  pool_kernel<<<BB, 128, 0, stream>>>(bx, bp);
  cls_kernel<<<BB, 64, 0, stream>>>(bp, cW1, cb1, cW2, cb2, logits);
}

// Round 5
// 1635.013 us; speedup vs baseline: 1.2572x; 1.2572x over previous
//
#include <hip/hip_runtime.h>
#include <hip/hip_bf16.h>
#include <math.h>

#define BB 64
#define SS 512
#define HH 64
#define DD 128
#define NHD 8
#define ROWS (BB*SS)   // 32768

typedef unsigned short u16;
typedef __attribute__((ext_vector_type(8))) short bf16x8;
typedef __attribute__((ext_vector_type(4))) float f32x4;

__device__ __forceinline__ u16 f2b(float f) {
  union { float f; unsigned u; } x; x.f = f;
  unsigned r = x.u + 0x7fffu + ((x.u >> 16) & 1u);
  return (u16)(r >> 16);
}

__device__ __forceinline__ float fast_tanh(float x) {
  float ax = fminf(fabsf(x), 15.f);
  float e = __expf(2.f * ax);
  float r = 1.f - __fdividef(2.f, e + 1.f);
  return copysignf(r, x);
}

// ---------------------------------------------------------------------------
// SDE scan v5: one block per batch, 512 threads (8 waves = 2 waves/SIMD for
// latency hiding — round-3/4 post-mortem showed the kernel was LATENCY bound
// at 1 wave/SIMD, not LDS-throughput bound).
// Partition: stage A (layer1, 256 outs): 2 lanes/out, 1 shfl.
//            stage B (layer2, 128 outs): 4 lanes/out, 2 shfls.
//            stage C (layer3,  64 outs): 8 lanes/out, 3 shfls + update.
// Also emits bf16 sde features directly (replaces cast_kernel).
// ---------------------------------------------------------------------------
__global__ __launch_bounds__(512, 2) void sde_kernel(
    const float* __restrict__ ts, const float* __restrict__ noise,
    const float* __restrict__ dW1, const float* __restrict__ db1,
    const float* __restrict__ dW2, const float* __restrict__ db2,
    const float* __restrict__ dW3, const float* __restrict__ db3,
    const float* __restrict__ gW1, const float* __restrict__ gb1,
    const float* __restrict__ gW2, const float* __restrict__ gb2,
    const float* __restrict__ pmind, const float* __restrict__ pmaxd,
    float* __restrict__ out, u16* __restrict__ outB) {
  const int b = blockIdx.x, t = threadIdx.x;
  __shared__ float y_s[64];
  __shared__ float h1g1[256];           // h1[0..127], g1[128..255]
  __shared__ float h2s[64], gcs[64];
  __shared__ float tl_s[512], hs_s[512], sq_s[512];

  const float mind = fabsf(pmind[0]);
  const float maxd = fabsf(pmaxd[0]);

  // ---- stage-A: output oA = t>>1, k-half hA = t&1 ----
  const int oA = t >> 1, hA = t & 1;
  const int cA = oA & 127;
  const float* W1 = (oA < 128) ? dW1 : gW1;
  float wA[32];
#pragma unroll
  for (int k = 0; k < 32; k++) wA[k] = W1[(hA * 32 + k) * 128 + cA];
  const float wAt = W1[64 * 128 + cA];
  const float bA = ((oA < 128) ? db1 : gb1)[cA];

  // ---- stage-B: output oB = t>>2, k-quarter qB = t&3 ----
  const int oB = t >> 2, qB = t & 3;
  const int cB = oB & 63;
  const float* W2 = (oB < 64) ? dW2 : gW2;
  float wB[32];
#pragma unroll
  for (int k = 0; k < 32; k++) wB[k] = W2[(qB * 32 + k) * 64 + cB];
  const float bB = ((oB < 64) ? db2 : gb2)[cB];

  // ---- stage-C: output cC = t>>3, k-eighth qC = t&7 ----
  const int cC = t >> 3, qC = t & 7;
  float wC[8];
#pragma unroll
  for (int k = 0; k < 8; k++) wC[k] = dW3[(qC * 8 + k) * 64 + cC];
  const float bC = db3[cC];

  // ---- prologue ----
  if (t < 512) tl_s[t] = ts[t * 3];
  __syncthreads();
  if (t < 511) {
    float hh = tl_s[t + 1] - tl_s[t];
    hs_s[t] = hh;
    sq_s[t] = sqrtf(hh);
  }
  if (t < 64) {
    float y = 0.1f;
    if (t < 3) y = fminf(fmaxf(ts[b * 1536 + t], 0.01f), 10.f);
    y_s[t] = y;
    out[(long)b * 32768 + t] = y;
    outB[((long)b * 512) * 64 + t] = f2b(y);
  }
  float nz = noise[b * 64 + cC];
  __syncthreads();

  for (int i = 0; i < 511; i++) {
    float nzn = 0.f;
    if (i < 510) nzn = noise[(long)(i + 1) * 4096 + b * 64 + cC];
    const float tl = tl_s[i];
    const float hh = hs_s[i];
    const float sq = sq_s[i];

    // ---- stage A: layer 1, 32 FMA + 1 shfl ----
    float a0 = 0.f, a1 = 0.f, a2 = 0.f, a3 = 0.f;
#pragma unroll
    for (int g = 0; g < 8; g++) {
      float4 yv = *(const float4*)&y_s[hA * 32 + g * 4];
      a0 += yv.x * wA[g * 4 + 0];
      a1 += yv.y * wA[g * 4 + 1];
      a2 += yv.z * wA[g * 4 + 2];
      a3 += yv.w * wA[g * 4 + 3];
    }
    float p1 = (a0 + a1) + (a2 + a3);
    if (hA == 0) p1 += tl * wAt + bA;
    p1 += __shfl_xor(p1, 1);
    if (hA == 0) h1g1[oA] = fast_tanh(p1);
    __syncthreads();                       // barrier 1

    // ---- stage B: layer 2, 32 FMA + 2 shfls ----
    const float* srcB = h1g1 + ((oB < 64) ? 0 : 128) + qB * 32;
    float c0 = 0.f, c1 = 0.f, c2 = 0.f, c3 = 0.f;
#pragma unroll
    for (int g = 0; g < 8; g++) {
      float4 xv = *(const float4*)&srcB[g * 4];
      c0 += xv.x * wB[g * 4 + 0];
      c1 += xv.y * wB[g * 4 + 1];
      c2 += xv.z * wB[g * 4 + 2];
      c3 += xv.w * wB[g * 4 + 3];
    }
    float p2 = (c0 + c1) + (c2 + c3);
    p2 += __shfl_xor(p2, 1);
    p2 += __shfl_xor(p2, 2);
    if (qB == 0) {
      p2 += bB;
      if (oB < 64) {
        h2s[cB] = fast_tanh(p2);
      } else {
        gcs[cB] = fmaxf(p2, 0.f) + __logf(1.f + __expf(-fabsf(p2))) + mind;
      }
    }
    __syncthreads();                       // barrier 2

    // ---- stage C: layer 3, 8 FMA + 3 shfls + update ----
    float d0 = 0.f, d1 = 0.f;
#pragma unroll
    for (int g = 0; g < 2; g++) {
      float4 hv = *(const float4*)&h2s[qC * 8 + g * 4];
      d0 += hv.x * wC[g * 4 + 0];
      d0 += hv.y * wC[g * 4 + 1];
      d1 += hv.z * wC[g * 4 + 2];
      d1 += hv.w * wC[g * 4 + 3];
    }
    float p3 = d0 + d1;
    p3 += __shfl_xor(p3, 1);
    p3 += __shfl_xor(p3, 2);
    p3 += __shfl_xor(p3, 4);
    if (qC == 0) {
      float dc = fminf(fmaxf(p3 + bC, -maxd), maxd);
      float yo = y_s[cC];
      float gg = gcs[cC] * fminf(fmaxf(yo, -10.f), 10.f);
      float yn = yo + dc * yo * hh + gg * nz * sq;
      yn = fminf(fmaxf(yn, 0.01f), 10.f);
      y_s[cC] = yn;
      out[(long)b * 32768 + (i + 1) * 64 + cC] = yn;
      outB[((long)b * 512 + i + 1) * 64 + cC] = f2b(yn);
    }
    nz = nzn;
    __syncthreads();                       // barrier 3 (y_s ready for stage A)
  }
}

// ---------------------------------------------------------------------------
// Weight prep: cast fp32 -> bf16 and transpose [K][N] -> [N][K].
// QKV packed contiguously per layer: [layer][ q(128x128) k v ] for fused GEMM.
// ---------------------------------------------------------------------------
__global__ __launch_bounds__(256) void prep_weights(
    const float* __restrict__ in_W, const float* __restrict__ Wq,
    const float* __restrict__ Wk, const float* __restrict__ Wv,
    const float* __restrict__ Wo, const float* __restrict__ fW1,
    const float* __restrict__ fW2,
    u16* __restrict__ inWt, u16* __restrict__ qkvWt, u16* __restrict__ Wot,
    u16* __restrict__ fW1t, u16* __restrict__ fW2t) {
  const int z = blockIdx.z, layer = blockIdx.y, tile = blockIdx.x;
  const float* src; u16* dst; int R, C, nl;
  switch (z) {
    case 0: src = in_W; dst = inWt; R = 64; C = 128; nl = 1; break;
    case 1: src = Wq + layer * 16384; dst = qkvWt + layer * 49152; R = 128; C = 128; nl = 4; break;
    case 2: src = Wk + layer * 16384; dst = qkvWt + layer * 49152 + 16384; R = 128; C = 128; nl = 4; break;
    case 3: src = Wv + layer * 16384; dst = qkvWt + layer * 49152 + 32768; R = 128; C = 128; nl = 4; break;
    case 4: src = Wo + layer * 16384; dst = Wot + layer * 16384; R = 128; C = 128; nl = 4; break;
    case 5: src = fW1 + layer * 65536; dst = fW1t + layer * 65536; R = 128; C = 512; nl = 4; break;
    default: src = fW2 + layer * 65536; dst = fW2t + layer * 65536; R = 512; C = 128; nl = 4; break;
  }
  const int nt = (R / 32) * (C / 32);
  if (layer >= nl || tile >= nt) return;
  const int tpr = C / 32;
  const int r0 = (tile / tpr) * 32, c0 = (tile % tpr) * 32;
  __shared__ float tl[32][33];
  const int tx = threadIdx.x & 31, ty = threadIdx.x >> 5;
#pragma unroll
  for (int p = 0; p < 4; p++)
    tl[ty + 8 * p][tx] = src[(long)(r0 + ty + 8 * p) * C + c0 + tx];
  __syncthreads();
#pragma unroll
  for (int p = 0; p < 4; p++)
    dst[(long)(c0 + ty + 8 * p) * R + r0 + tx] = f2b(tl[tx][ty + 8 * p]);
}

// combined qkv bias [4][384]
__global__ __launch_bounds__(384) void prep_bias(
    const float* __restrict__ bq, const float* __restrict__ bk,
    const float* __restrict__ bv, float* __restrict__ bqkv) {
  const int l = blockIdx.x, c = threadIdx.x;
  float v;
  if (c < 128) v = bq[l * 128 + c];
  else if (c < 256) v = bk[l * 128 + c - 128];
  else v = bv[l * 128 + c - 256];
  bqkv[l * 384 + c] = v;
}

// ---------------------------------------------------------------------------
// bf16 MFMA GEMM: C[M,N] = A[M,K] @ Bt[N,K]^T + bias.
// MODE 0: fp32 out. MODE 1: bf16 out + relu. MODE 2: fp32+bf16. MODE 3: bf16.
// ---------------------------------------------------------------------------
template <int MODE>
__global__ __launch_bounds__(256) void mfma_gemm(
    const u16* __restrict__ A, const u16* __restrict__ Bt,
    const float* __restrict__ bias, float* __restrict__ outF,
    u16* __restrict__ outB, int K, int N) {
  __shared__ u16 As[128 * 40];
  __shared__ u16 Bs[64 * 40];
  const int t = threadIdx.x;
  const int nb = blockIdx.x * 64;
  const long mb = (long)blockIdx.y * 128;
  const int lane = t & 63, wave = t >> 6;
  const int wm = (wave >> 1) * 64, wn = (wave & 1) * 32;
  const int fr = lane & 15, quad = lane >> 4;

  f32x4 zero = {0.f, 0.f, 0.f, 0.f};
  f32x4 acc[4][2];
#pragma unroll
  for (int mi = 0; mi < 4; mi++)
#pragma unroll
    for (int ni = 0; ni < 2; ni++) acc[mi][ni] = zero;

  for (int k0 = 0; k0 < K; k0 += 32) {
#pragma unroll
    for (int p = 0; p < 2; p++) {
      int idx = t + p * 256, row = idx >> 2, seg = idx & 3;
      int4 v = *(const int4*)&A[(mb + row) * K + k0 + seg * 8];
      *(int4*)&As[row * 40 + seg * 8] = v;
    }
    {
      int row = t >> 2, seg = t & 3;
      int4 v = *(const int4*)&Bt[(long)(nb + row) * K + k0 + seg * 8];
      *(int4*)&Bs[row * 40 + seg * 8] = v;
    }
    __syncthreads();
    bf16x8 af[4], bfr[2];
#pragma unroll
    for (int mi = 0; mi < 4; mi++)
      af[mi] = *(const bf16x8*)&As[(wm + mi * 16 + fr) * 40 + quad * 8];
#pragma unroll
    for (int ni = 0; ni < 2; ni++)
      bfr[ni] = *(const bf16x8*)&Bs[(wn + ni * 16 + fr) * 40 + quad * 8];
#pragma unroll
    for (int mi = 0; mi < 4; mi++)
#pragma unroll
      for (int ni = 0; ni < 2; ni++)
        acc[mi][ni] = __builtin_amdgcn_mfma_f32_16x16x32_bf16(
            af[mi], bfr[ni], acc[mi][ni], 0, 0, 0);
    __syncthreads();
  }

#pragma unroll
  for (int mi = 0; mi < 4; mi++)
#pragma unroll
    for (int ni = 0; ni < 2; ni++) {
      int col = nb + wn + ni * 16 + fr;
      float bv = bias[col];
#pragma unroll
      for (int r = 0; r < 4; r++) {
        long row = mb + wm + mi * 16 + quad * 4 + r;
        float v = acc[mi][ni][r] + bv;
        if (MODE == 0) {
          outF[row * N + col] = v;
        } else if (MODE == 1) {
          outB[row * N + col] = f2b(fmaxf(v, 0.f));
        } else if (MODE == 2) {
          outF[row * N + col] = v;
          outB[row * N + col] = f2b(v);
        } else {
          outB[row * N + col] = f2b(v);
        }
      }
    }
}

// ---------------------------------------------------------------------------
// Flash attention, bf16 MFMA, dh=16. Input is packed QKV [row][384]
// (Q at +0, K at +128, V at +256). One block per (b,h).
// ---------------------------------------------------------------------------
__global__ __launch_bounds__(256, 2) void attn_mfma(
    const u16* __restrict__ QKV, u16* __restrict__ Og) {
  const int bh = blockIdx.x;
  const int b = bh >> 3, h = bh & 7;
  __shared__ u16 Ks[512 * 24];
  __shared__ u16 Vt[16 * 520];
  __shared__ u16 Pb[4][16 * 40];
  const int t = threadIdx.x;
  const int w = t >> 6, lane = t & 63;
  const int m = lane & 15, quad = lane >> 4;
  const long qbase = ((long)b * SS) * 384 + h * 16;
  const long obase = ((long)b * SS) * DD + h * 16;

  for (int i = t; i < 1024; i += 256) {
    int row = i >> 1, half = i & 1;
    *(int4*)&Ks[row * 24 + half * 8] =
        *(const int4*)&QKV[qbase + 128 + (long)row * 384 + half * 8];
    u16 v8[8];
    *(int4*)v8 = *(const int4*)&QKV[qbase + 256 + (long)row * 384 + half * 8];
#pragma unroll
    for (int jj = 0; jj < 8; jj++) Vt[(half * 8 + jj) * 520 + row] = v8[jj];
  }
  __syncthreads();

  const float scale = 0.25f;   // 1/sqrt(16)
  for (int qt = w; qt < 32; qt += 4) {
    const int q0 = qt * 16;
    bf16x8 qf = {0, 0, 0, 0, 0, 0, 0, 0};
    if (quad < 2)
      qf = *(const bf16x8*)&QKV[qbase + (long)(q0 + m) * 384 + quad * 8];
    f32x4 oacc = {0.f, 0.f, 0.f, 0.f};
    float mrun[4] = {-1e30f, -1e30f, -1e30f, -1e30f};
    float lrun[4] = {0.f, 0.f, 0.f, 0.f};

    for (int kt = 0; kt < 16; kt++) {
      const int k0 = kt * 32;
      bf16x8 kf0 = {0, 0, 0, 0, 0, 0, 0, 0};
      bf16x8 kf1 = {0, 0, 0, 0, 0, 0, 0, 0};
      if (quad < 2) {
        kf0 = *(const bf16x8*)&Ks[(k0 + m) * 24 + quad * 8];
        kf1 = *(const bf16x8*)&Ks[(k0 + 16 + m) * 24 + quad * 8];
      }
      f32x4 z4 = {0.f, 0.f, 0.f, 0.f};
      f32x4 slo = __builtin_amdgcn_mfma_f32_16x16x32_bf16(qf, kf0, z4, 0, 0, 0);
      f32x4 shi = __builtin_amdgcn_mfma_f32_16x16x32_bf16(qf, kf1, z4, 0, 0, 0);
      u16* pb = &Pb[w][0];
#pragma unroll
      for (int r = 0; r < 4; r++) {
        float sl = slo[r] * scale, sh = shi[r] * scale;
        float mx = fmaxf(sl, sh);
        mx = fmaxf(mx, __shfl_xor(mx, 1));
        mx = fmaxf(mx, __shfl_xor(mx, 2));
        mx = fmaxf(mx, __shfl_xor(mx, 4));
        mx = fmaxf(mx, __shfl_xor(mx, 8));
        float nm = fmaxf(mrun[r], mx);
        float alpha = __expf(mrun[r] - nm);
        mrun[r] = nm;
        float pl = __expf(sl - nm), ph = __expf(sh - nm);
        float rs = pl + ph;
        rs += __shfl_xor(rs, 1);
        rs += __shfl_xor(rs, 2);
        rs += __shfl_xor(rs, 4);
        rs += __shfl_xor(rs, 8);
        lrun[r] = lrun[r] * alpha + rs;
        oacc[r] *= alpha;
        int prow = quad * 4 + r;
        pb[prow * 40 + m] = f2b(pl);
        pb[prow * 40 + 16 + m] = f2b(ph);
      }
      __builtin_amdgcn_s_waitcnt(0xC07F);   // lgkmcnt(0)
      bf16x8 pf = *(const bf16x8*)&pb[m * 40 + quad * 8];
      bf16x8 vf = *(const bf16x8*)&Vt[m * 520 + k0 + quad * 8];
      oacc = __builtin_amdgcn_mfma_f32_16x16x32_bf16(pf, vf, oacc, 0, 0, 0);
    }

#pragma unroll
    for (int r = 0; r < 4; r++) {
      float inv = __fdividef(1.f, lrun[r]);
      Og[obase + (long)(q0 + quad * 4 + r) * DD + m] = f2b(oacc[r] * inv);
    }
  }
}

// ---------------------------------------------------------------------------
__global__ __launch_bounds__(256) void ln_add_kernel(
    const float* __restrict__ X, const float* __restrict__ R,
    const float* __restrict__ gamma, const float* __restrict__ beta,
    float* __restrict__ Out, u16* __restrict__ OutB) {
  const int t = threadIdx.x;
  const int wave = t >> 6, lane = t & 63;
  const long row = (long)blockIdx.x * 4 + wave;
  const long off = row * DD + lane * 2;
  float2 xv = *(const float2*)&X[off];
  float2 rv = *(const float2*)&R[off];
  float a0 = xv.x + rv.x, a1 = xv.y + rv.y;
  float s = a0 + a1, ss = a0 * a0 + a1 * a1;
#pragma unroll
  for (int o = 1; o < 64; o <<= 1) {
    s += __shfl_xor(s, o);
    ss += __shfl_xor(ss, o);
  }
  float mean = s * (1.f / 128.f);
  float var = ss * (1.f / 128.f) - mean * mean;
  float rstd = rsqrtf(var + 1e-5f);
  float2 o;
  o.x = (a0 - mean) * rstd * gamma[lane * 2] + beta[lane * 2];
  o.y = (a1 - mean) * rstd * gamma[lane * 2 + 1] + beta[lane * 2 + 1];
  *(float2*)&Out[off] = o;
  ushort2 ob; ob.x = f2b(o.x); ob.y = f2b(o.y);
  *(ushort2*)&OutB[off] = ob;
}

// ---------------------------------------------------------------------------
__global__ __launch_bounds__(128) void pool_kernel(const float* __restrict__ X,
                                                   float* __restrict__ P) {
  const int b = blockIdx.x, c = threadIdx.x;
  float acc = 0.f;
  for (int s = 0; s < SS; s++) acc += X[((long)b * SS + s) * DD + c];
  P[b * DD + c] = acc * (1.f / 512.f);
}

__global__ __launch_bounds__(64) void cls_kernel(
    const float* __restrict__ P, const float* __restrict__ W1,
    const float* __restrict__ b1, const float* __restrict__ W2,
    const float* __restrict__ b2, float* __restrict__ L) {
  const int b = blockIdx.x, t = threadIdx.x;
  __shared__ float sp[128];
  __shared__ float sh[64];
  sp[t] = P[b * DD + t];
  sp[t + 64] = P[b * DD + 64 + t];
  __syncthreads();
  float acc = b1[t];
  for (int k = 0; k < 128; k++) acc += sp[k] * W1[k * 64 + t];
  sh[t] = fmaxf(acc, 0.f);
  __syncthreads();
  if (t < 5) {
    float acc2 = b2[t];
    for (int k = 0; k < 64; k++) acc2 += sh[k] * W2[k * 5 + t];
    L[b * 5 + t] = acc2;
  }
}

// ---------------------------------------------------------------------------
extern "C" void kernel_launch(void* const* d_in, const int* in_sizes, int n_in,
                              void* d_out, int out_size, void* d_ws, size_t ws_size,
                              hipStream_t stream) {
  const float* ts    = (const float*)d_in[0];
  const float* noise = (const float*)d_in[2];
  const float* dW1   = (const float*)d_in[3];
  const float* db1   = (const float*)d_in[4];
  const float* dW2   = (const float*)d_in[5];
  const float* db2   = (const float*)d_in[6];
  const float* dW3   = (const float*)d_in[7];
  const float* db3   = (const float*)d_in[8];
  const float* gW1   = (const float*)d_in[9];
  const float* gb1   = (const float*)d_in[10];
  const float* gW2   = (const float*)d_in[11];
  const float* gb2   = (const float*)d_in[12];
  const float* mind  = (const float*)d_in[13];
  const float* maxd  = (const float*)d_in[14];
  const float* in_W  = (const float*)d_in[15];
  const float* in_b  = (const float*)d_in[16];
  const float* Wq    = (const float*)d_in[17];
  const float* bq    = (const float*)d_in[18];
  const float* Wk    = (const float*)d_in[19];
  const float* bk    = (const float*)d_in[20];
  const float* Wv    = (const float*)d_in[21];
  const float* bv    = (const float*)d_in[22];
  const float* Wo    = (const float*)d_in[23];
  const float* bo    = (const float*)d_in[24];
  const float* ln1s  = (const float*)d_in[25];
  const float* ln1b  = (const float*)d_in[26];
  const float* fW1   = (const float*)d_in[27];
  const float* fb1   = (const float*)d_in[28];
  const float* fW2   = (const float*)d_in[29];
  const float* fb2   = (const float*)d_in[30];
  const float* ln2s  = (const float*)d_in[31];
  const float* ln2b  = (const float*)d_in[32];
  const float* cW1   = (const float*)d_in[33];
  const float* cb1   = (const float*)d_in[34];
  const float* cW2   = (const float*)d_in[35];
  const float* cb2   = (const float*)d_in[36];

  float* logits = (float*)d_out;
  float* sde    = logits + BB * 5;

  // Workspace layout (<= ~86 MB):
  char* W = (char*)d_ws;
  float* bx    = (float*)(W);                 // 16 MB fp32 x
  u16*  bxb    = (u16*)(W + (16u << 20));     //  8 MB bf16 x
  u16*  bqkvb  = (u16*)(W + (24u << 20));     // 25.2 MB bf16 packed QKV [row][384]
  u16*  bh     = (u16*)(W + (24u << 20));     // 32 MB bf16 FFN hidden (alias, post-attn)
  u16*  bob    = (u16*)(W + (56u << 20));     //  8 MB bf16 attn out
  float* bqf   = (float*)(W + (64u << 20));   // 16 MB fp32 (O-proj / FFN2 out)
  u16*  bsb    = (u16*)(W + (80u << 20));     //  4 MB bf16 sde feats
  u16*  wts    = (u16*)(W + (84u << 20));     // ~1.5 MB bf16 weights
  float* bqkv_bias = (float*)(W + (86u << 20));  // 6 KB
  float* bp    = bqkv_bias + 4 * 384;         // pooled 64x128

  u16* inWt  = wts;                 // [128][64]
  u16* qkvWt = inWt + 8192;         // [4][3][128][128]
  u16* Wot   = qkvWt + 196608;      // [4][128][128]
  u16* fW1t  = Wot + 65536;         // [4][512][128]
  u16* fW2t  = fW1t + 262144;       // [4][128][512]

  prep_weights<<<dim3(64, 4, 7), 256, 0, stream>>>(in_W, Wq, Wk, Wv, Wo, fW1, fW2,
                                                   inWt, qkvWt, Wot, fW1t, fW2t);
  prep_bias<<<4, 384, 0, stream>>>(bq, bk, bv, bqkv_bias);

  sde_kernel<<<64, 512, 0, stream>>>(ts, noise, dW1, db1, dW2, db2, dW3, db3,
                                     gW1, gb1, gW2, gb2, mind, maxd, sde, bsb);

  // x = sde @ in_W + in_b  (dual fp32+bf16 output)
  mfma_gemm<2><<<dim3(2, 256), 256, 0, stream>>>(bsb, inWt, in_b, bx, bxb, 64, 128);

  for (int l = 0; l < 4; l++) {
    // fused QKV: [32768x128] @ [128x384]
    mfma_gemm<3><<<dim3(6, 256), 256, 0, stream>>>(bxb, qkvWt + l * 49152,
                                                   bqkv_bias + l * 384, nullptr,
                                                   bqkvb, 128, 384);
    attn_mfma<<<BB * NHD, 256, 0, stream>>>(bqkvb, bob);
    mfma_gemm<0><<<dim3(2, 256), 256, 0, stream>>>(bob, Wot + l * 16384, bo + l * DD, bqf, nullptr, 128, 128);
    ln_add_kernel<<<ROWS / 4, 256, 0, stream>>>(bx, bqf, ln1s + l * DD, ln1b + l * DD, bx, bxb);
    mfma_gemm<1><<<dim3(8, 256), 256, 0, stream>>>(bxb, fW1t + l * 65536, fb1 + l * 512, nullptr, bh, 128, 512);
    mfma_gemm<0><<<dim3(2, 256), 256, 0, stream>>>(bh, fW2t + l * 65536, fb2 + l * DD, bqf, nullptr, 512, 128);
    ln_add_kernel<<<ROWS / 4, 256, 0, stream>>>(bx, bqf, ln2s + l * DD, ln2b + l * DD, bx, bxb);
  }

  pool_kernel<<<BB, 128, 0, stream>>>(bx, bp);
  cls_kernel<<<BB, 64, 0, stream>>>(bp, cW1, cb1, cW2, cb2, logits);
}

// Round 7
// 1562.123 us; speedup vs baseline: 1.3159x; 1.0467x over previous
//
#include <hip/hip_runtime.h>
#include <hip/hip_bf16.h>
#include <math.h>

#define BB 64
#define SS 512
#define HH 64
#define DD 128
#define NHD 8
#define ROWS (BB*SS)   // 32768
#define HMSZ 4194304   // u16 elems per head-major Q/K/V buffer (64*8*512*16)

typedef unsigned short u16;
typedef __attribute__((ext_vector_type(8))) short bf16x8;
typedef __attribute__((ext_vector_type(4))) float f32x4;

__device__ __forceinline__ u16 f2b(float f) {
  union { float f; unsigned u; } x; x.f = f;
  unsigned r = x.u + 0x7fffu + ((x.u >> 16) & 1u);
  return (u16)(r >> 16);
}

__device__ __forceinline__ float fast_tanh(float x) {
  float ax = fminf(fabsf(x), 15.f);
  float e = __expf(2.f * ax);
  float r = 1.f - __fdividef(2.f, e + 1.f);
  return copysignf(r, x);
}

// LDS-only barrier (CK block_sync_lds pattern): does NOT drain vmcnt, so
// global prefetches/stores float across. __syncthreads() drains vmcnt(0),
// which serialized the SDE loop on its own noise prefetch + output stores.
__device__ __forceinline__ void barrier_lds() {
  __builtin_amdgcn_s_waitcnt(0xC07F);   // lgkmcnt(0) only
  __builtin_amdgcn_s_barrier();
}

// ---------------------------------------------------------------------------
// SDE scan v6: identical partition to v5 (512 thr, 2 waves/SIMD), but all
// in-loop barriers are LDS-only.
// ---------------------------------------------------------------------------
__global__ __launch_bounds__(512, 2) void sde_kernel(
    const float* __restrict__ ts, const float* __restrict__ noise,
    const float* __restrict__ dW1, const float* __restrict__ db1,
    const float* __restrict__ dW2, const float* __restrict__ db2,
    const float* __restrict__ dW3, const float* __restrict__ db3,
    const float* __restrict__ gW1, const float* __restrict__ gb1,
    const float* __restrict__ gW2, const float* __restrict__ gb2,
    const float* __restrict__ pmind, const float* __restrict__ pmaxd,
    float* __restrict__ out, u16* __restrict__ outB) {
  const int b = blockIdx.x, t = threadIdx.x;
  __shared__ float y_s[64];
  __shared__ float h1g1[256];
  __shared__ float h2s[64], gcs[64];
  __shared__ float tl_s[512], hs_s[512], sq_s[512];

  const float mind = fabsf(pmind[0]);
  const float maxd = fabsf(pmaxd[0]);

  const int oA = t >> 1, hA = t & 1;
  const int cA = oA & 127;
  const float* W1 = (oA < 128) ? dW1 : gW1;
  float wA[32];
#pragma unroll
  for (int k = 0; k < 32; k++) wA[k] = W1[(hA * 32 + k) * 128 + cA];
  const float wAt = W1[64 * 128 + cA];
  const float bA = ((oA < 128) ? db1 : gb1)[cA];

  const int oB = t >> 2, qB = t & 3;
  const int cB = oB & 63;
  const float* W2 = (oB < 64) ? dW2 : gW2;
  float wB[32];
#pragma unroll
  for (int k = 0; k < 32; k++) wB[k] = W2[(qB * 32 + k) * 64 + cB];
  const float bB = ((oB < 64) ? db2 : gb2)[cB];

  const int cC = t >> 3, qC = t & 7;
  float wC[8];
#pragma unroll
  for (int k = 0; k < 8; k++) wC[k] = dW3[(qC * 8 + k) * 64 + cC];
  const float bC = db3[cC];

  // ---- prologue ----
  tl_s[t] = ts[t * 3];
  __syncthreads();
  if (t < 511) {
    float hh = tl_s[t + 1] - tl_s[t];
    hs_s[t] = hh;
    sq_s[t] = sqrtf(hh);
  }
  if (t < 64) {
    float y = 0.1f;
    if (t < 3) y = fminf(fmaxf(ts[b * 1536 + t], 0.01f), 10.f);
    y_s[t] = y;
    out[(long)b * 32768 + t] = y;
    outB[((long)b * 512) * 64 + t] = f2b(y);
  }
  float nz = noise[b * 64 + cC];
  __syncthreads();

  for (int i = 0; i < 511; i++) {
    float nzn = 0.f;
    if (i < 510) nzn = noise[(long)(i + 1) * 4096 + b * 64 + cC];
    const float tl = tl_s[i];
    const float hh = hs_s[i];
    const float sq = sq_s[i];

    // ---- stage A ----
    float a0 = 0.f, a1 = 0.f, a2 = 0.f, a3 = 0.f;
#pragma unroll
    for (int g = 0; g < 8; g++) {
      float4 yv = *(const float4*)&y_s[hA * 32 + g * 4];
      a0 += yv.x * wA[g * 4 + 0];
      a1 += yv.y * wA[g * 4 + 1];
      a2 += yv.z * wA[g * 4 + 2];
      a3 += yv.w * wA[g * 4 + 3];
    }
    float p1 = (a0 + a1) + (a2 + a3);
    if (hA == 0) p1 += tl * wAt + bA;
    p1 += __shfl_xor(p1, 1);
    if (hA == 0) h1g1[oA] = fast_tanh(p1);
    barrier_lds();                        // barrier 1

    // ---- stage B ----
    const float* srcB = h1g1 + ((oB < 64) ? 0 : 128) + qB * 32;
    float c0 = 0.f, c1 = 0.f, c2 = 0.f, c3 = 0.f;
#pragma unroll
    for (int g = 0; g < 8; g++) {
      float4 xv = *(const float4*)&srcB[g * 4];
      c0 += xv.x * wB[g * 4 + 0];
      c1 += xv.y * wB[g * 4 + 1];
      c2 += xv.z * wB[g * 4 + 2];
      c3 += xv.w * wB[g * 4 + 3];
    }
    float p2 = (c0 + c1) + (c2 + c3);
    p2 += __shfl_xor(p2, 1);
    p2 += __shfl_xor(p2, 2);
    if (qB == 0) {
      p2 += bB;
      if (oB < 64) {
        h2s[cB] = fast_tanh(p2);
      } else {
        gcs[cB] = fmaxf(p2, 0.f) + __logf(1.f + __expf(-fabsf(p2))) + mind;
      }
    }
    barrier_lds();                        // barrier 2

    // ---- stage C ----
    float d0 = 0.f, d1 = 0.f;
#pragma unroll
    for (int g = 0; g < 2; g++) {
      float4 hv = *(const float4*)&h2s[qC * 8 + g * 4];
      d0 += hv.x * wC[g * 4 + 0];
      d0 += hv.y * wC[g * 4 + 1];
      d1 += hv.z * wC[g * 4 + 2];
      d1 += hv.w * wC[g * 4 + 3];
    }
    float p3 = d0 + d1;
    p3 += __shfl_xor(p3, 1);
    p3 += __shfl_xor(p3, 2);
    p3 += __shfl_xor(p3, 4);
    if (qC == 0) {
      float dc = fminf(fmaxf(p3 + bC, -maxd), maxd);
      float yo = y_s[cC];
      float gg = gcs[cC] * fminf(fmaxf(yo, -10.f), 10.f);
      float yn = yo + dc * yo * hh + gg * nz * sq;
      yn = fminf(fmaxf(yn, 0.01f), 10.f);
      y_s[cC] = yn;
      out[(long)b * 32768 + (i + 1) * 64 + cC] = yn;
      outB[((long)b * 512 + i + 1) * 64 + cC] = f2b(yn);
    }
    nz = nzn;
    barrier_lds();                        // barrier 3
  }
}

// ---------------------------------------------------------------------------
// Weight prep (cast fp32 -> bf16 and transpose [K][N] -> [N][K]).
// ---------------------------------------------------------------------------
__global__ __launch_bounds__(256) void prep_weights(
    const float* __restrict__ in_W, const float* __restrict__ Wq,
    const float* __restrict__ Wk, const float* __restrict__ Wv,
    const float* __restrict__ Wo, const float* __restrict__ fW1,
    const float* __restrict__ fW2,
    u16* __restrict__ inWt, u16* __restrict__ qkvWt, u16* __restrict__ Wot,
    u16* __restrict__ fW1t, u16* __restrict__ fW2t) {
  const int z = blockIdx.z, layer = blockIdx.y, tile = blockIdx.x;
  const float* src; u16* dst; int R, C, nl;
  switch (z) {
    case 0: src = in_W; dst = inWt; R = 64; C = 128; nl = 1; break;
    case 1: src = Wq + layer * 16384; dst = qkvWt + layer * 49152; R = 128; C = 128; nl = 4; break;
    case 2: src = Wk + layer * 16384; dst = qkvWt + layer * 49152 + 16384; R = 128; C = 128; nl = 4; break;
    case 3: src = Wv + layer * 16384; dst = qkvWt + layer * 49152 + 32768; R = 128; C = 128; nl = 4; break;
    case 4: src = Wo + layer * 16384; dst = Wot + layer * 16384; R = 128; C = 128; nl = 4; break;
    case 5: src = fW1 + layer * 65536; dst = fW1t + layer * 65536; R = 128; C = 512; nl = 4; break;
    default: src = fW2 + layer * 65536; dst = fW2t + layer * 65536; R = 512; C = 128; nl = 4; break;
  }
  const int nt = (R / 32) * (C / 32);
  if (layer >= nl || tile >= nt) return;
  const int tpr = C / 32;
  const int r0 = (tile / tpr) * 32, c0 = (tile % tpr) * 32;
  __shared__ float tl[32][33];
  const int tx = threadIdx.x & 31, ty = threadIdx.x >> 5;
#pragma unroll
  for (int p = 0; p < 4; p++)
    tl[ty + 8 * p][tx] = src[(long)(r0 + ty + 8 * p) * C + c0 + tx];
  __syncthreads();
#pragma unroll
  for (int p = 0; p < 4; p++)
    dst[(long)(c0 + ty + 8 * p) * R + r0 + tx] = f2b(tl[tx][ty + 8 * p]);
}

__global__ __launch_bounds__(384) void prep_bias(
    const float* __restrict__ bq, const float* __restrict__ bk,
    const float* __restrict__ bv, float* __restrict__ bqkv) {
  const int l = blockIdx.x, c = threadIdx.x;
  float v;
  if (c < 128) v = bq[l * 128 + c];
  else if (c < 256) v = bk[l * 128 + c - 128];
  else v = bv[l * 128 + c - 256];
  bqkv[l * 384 + c] = v;
}

// ---------------------------------------------------------------------------
// bf16 MFMA GEMM: C[M,N] = A[M,K] @ Bt[N,K]^T + bias.  Tile 128x64.
// MODE 0: fp32. MODE 1: bf16+relu. MODE 2: fp32+bf16. MODE 3: bf16.
// MODE 4: bf16 scattered to head-major Q/K/V buffers (N=384 QKV GEMM).
// ---------------------------------------------------------------------------
template <int MODE>
__global__ __launch_bounds__(256) void mfma_gemm(
    const u16* __restrict__ A, const u16* __restrict__ Bt,
    const float* __restrict__ bias, float* __restrict__ outF,
    u16* __restrict__ outB, int K, int N) {
  __shared__ u16 As[128 * 40];
  __shared__ u16 Bs[64 * 40];
  const int t = threadIdx.x;
  const int nb = blockIdx.x * 64;
  const long mb = (long)blockIdx.y * 128;
  const int lane = t & 63, wave = t >> 6;
  const int wm = (wave >> 1) * 64, wn = (wave & 1) * 32;
  const int fr = lane & 15, quad = lane >> 4;

  f32x4 zero = {0.f, 0.f, 0.f, 0.f};
  f32x4 acc[4][2];
#pragma unroll
  for (int mi = 0; mi < 4; mi++)
#pragma unroll
    for (int ni = 0; ni < 2; ni++) acc[mi][ni] = zero;

  for (int k0 = 0; k0 < K; k0 += 32) {
#pragma unroll
    for (int p = 0; p < 2; p++) {
      int idx = t + p * 256, row = idx >> 2, seg = idx & 3;
      int4 v = *(const int4*)&A[(mb + row) * K + k0 + seg * 8];
      *(int4*)&As[row * 40 + seg * 8] = v;
    }
    {
      int row = t >> 2, seg = t & 3;
      int4 v = *(const int4*)&Bt[(long)(nb + row) * K + k0 + seg * 8];
      *(int4*)&Bs[row * 40 + seg * 8] = v;
    }
    __syncthreads();
    bf16x8 af[4], bfr[2];
#pragma unroll
    for (int mi = 0; mi < 4; mi++)
      af[mi] = *(const bf16x8*)&As[(wm + mi * 16 + fr) * 40 + quad * 8];
#pragma unroll
    for (int ni = 0; ni < 2; ni++)
      bfr[ni] = *(const bf16x8*)&Bs[(wn + ni * 16 + fr) * 40 + quad * 8];
#pragma unroll
    for (int mi = 0; mi < 4; mi++)
#pragma unroll
      for (int ni = 0; ni < 2; ni++)
        acc[mi][ni] = __builtin_amdgcn_mfma_f32_16x16x32_bf16(
            af[mi], bfr[ni], acc[mi][ni], 0, 0, 0);
    __syncthreads();
  }

#pragma unroll
  for (int mi = 0; mi < 4; mi++)
#pragma unroll
    for (int ni = 0; ni < 2; ni++) {
      int col = nb + wn + ni * 16 + fr;
      float bv = bias[col];
#pragma unroll
      for (int r = 0; r < 4; r++) {
        long row = mb + wm + mi * 16 + quad * 4 + r;
        float v = acc[mi][ni][r] + bv;
        if (MODE == 0) {
          outF[row * N + col] = v;
        } else if (MODE == 1) {
          outB[row * N + col] = f2b(fmaxf(v, 0.f));
        } else if (MODE == 2) {
          outF[row * N + col] = v;
          outB[row * N + col] = f2b(v);
        } else if (MODE == 3) {
          outB[row * N + col] = f2b(v);
        } else {
          // head-major scatter: which = col/128, h = (col/16)&7, d = col&15
          int which = col >> 7, h = (col >> 4) & 7, d = col & 15;
          long bidx = row >> 9, s = row & 511;
          outB[(long)which * HMSZ + (((bidx << 3) + h) << 13) + (s << 4) + d] =
              f2b(v);
        }
      }
    }
}

// ---------------------------------------------------------------------------
// Fused GEMM + residual + LayerNorm: y = LN(resid + A@Bt + bias)*gamma+beta.
// Tile 128x128 (full row), BK=32, 256 threads (2x2 waves of 64x64).
// Writes fp32 + bf16.
// ---------------------------------------------------------------------------
__global__ __launch_bounds__(256) void gemm_ln(
    const u16* __restrict__ A, const u16* __restrict__ Bt,
    const float* __restrict__ bias, const float* __restrict__ resid,
    const float* __restrict__ gamma, const float* __restrict__ beta,
    float* __restrict__ outF, u16* __restrict__ outB, int K) {
  __shared__ u16 As[128 * 40];
  __shared__ u16 Bs[128 * 40];
  __shared__ float s1[2][128], s2[2][128];
  const int t = threadIdx.x;
  const long mb = (long)blockIdx.x * 128;
  const int lane = t & 63, wave = t >> 6;
  const int wm = (wave >> 1) * 64, wn = (wave & 1) * 64;
  const int fr = lane & 15, quad = lane >> 4;

  f32x4 zero = {0.f, 0.f, 0.f, 0.f};
  f32x4 acc[4][4];
#pragma unroll
  for (int mi = 0; mi < 4; mi++)
#pragma unroll
    for (int ni = 0; ni < 4; ni++) acc[mi][ni] = zero;

  for (int k0 = 0; k0 < K; k0 += 32) {
#pragma unroll
    for (int p = 0; p < 2; p++) {
      int idx = t + p * 256, row = idx >> 2, seg = idx & 3;
      *(int4*)&As[row * 40 + seg * 8] =
          *(const int4*)&A[(mb + row) * K + k0 + seg * 8];
      *(int4*)&Bs[row * 40 + seg * 8] =
          *(const int4*)&Bt[(long)row * K + k0 + seg * 8];
    }
    __syncthreads();
    bf16x8 af[4], bfr[4];
#pragma unroll
    for (int mi = 0; mi < 4; mi++)
      af[mi] = *(const bf16x8*)&As[(wm + mi * 16 + fr) * 40 + quad * 8];
#pragma unroll
    for (int ni = 0; ni < 4; ni++)
      bfr[ni] = *(const bf16x8*)&Bs[(wn + ni * 16 + fr) * 40 + quad * 8];
#pragma unroll
    for (int mi = 0; mi < 4; mi++)
#pragma unroll
      for (int ni = 0; ni < 4; ni++)
        acc[mi][ni] = __builtin_amdgcn_mfma_f32_16x16x32_bf16(
            af[mi], bfr[ni], acc[mi][ni], 0, 0, 0);
    __syncthreads();
  }

  float bv[4], gv[4], be[4];
#pragma unroll
  for (int ni = 0; ni < 4; ni++) {
    int col = wn + ni * 16 + fr;
    bv[ni] = bias[col];
    gv[ni] = gamma[col];
    be[ni] = beta[col];
  }

  // v = acc + bias + resid; accumulate row stats (partial over this wave's 64 cols)
#pragma unroll
  for (int mi = 0; mi < 4; mi++) {
#pragma unroll
    for (int r = 0; r < 4; r++) {
      int rloc = wm + mi * 16 + quad * 4 + r;
      long row = mb + rloc;
      float s = 0.f, ss = 0.f;
#pragma unroll
      for (int ni = 0; ni < 4; ni++) {
        int col = wn + ni * 16 + fr;
        float v = acc[mi][ni][r] + bv[ni] + resid[row * DD + col];
        acc[mi][ni][r] = v;
        s += v;
        ss += v * v;
      }
      s += __shfl_xor(s, 1); ss += __shfl_xor(ss, 1);
      s += __shfl_xor(s, 2); ss += __shfl_xor(ss, 2);
      s += __shfl_xor(s, 4); ss += __shfl_xor(ss, 4);
      s += __shfl_xor(s, 8); ss += __shfl_xor(ss, 8);
      if (fr == 0) {
        s1[wn >> 6][rloc] = s;
        s2[wn >> 6][rloc] = ss;
      }
    }
  }
  __syncthreads();

#pragma unroll
  for (int mi = 0; mi < 4; mi++) {
#pragma unroll
    for (int r = 0; r < 4; r++) {
      int rloc = wm + mi * 16 + quad * 4 + r;
      long row = mb + rloc;
      float sum = s1[0][rloc] + s1[1][rloc];
      float sumsq = s2[0][rloc] + s2[1][rloc];
      float mean = sum * (1.f / 128.f);
      float var = sumsq * (1.f / 128.f) - mean * mean;
      float rstd = rsqrtf(var + 1e-5f);
#pragma unroll
      for (int ni = 0; ni < 4; ni++) {
        int col = wn + ni * 16 + fr;
        float o = (acc[mi][ni][r] - mean) * rstd * gv[ni] + be[ni];
        outF[row * DD + col] = o;
        outB[row * DD + col] = f2b(o);
      }
    }
  }
}

// ---------------------------------------------------------------------------
// Flash attention, bf16 MFMA, dh=16, head-major Q/K/V inputs (fully
// coalesced staging). One block per (b,h). Output row-major [row][128].
// ---------------------------------------------------------------------------
__global__ __launch_bounds__(256, 2) void attn_mfma(
    const u16* __restrict__ QKV, u16* __restrict__ Og) {
  const int bh = blockIdx.x;
  const int b = bh >> 3, h = bh & 7;
  __shared__ u16 Ks[512 * 24];
  __shared__ u16 Vt[16 * 520];
  __shared__ u16 Pb[4][16 * 40];
  const int t = threadIdx.x;
  const int w = t >> 6, lane = t & 63;
  const int m = lane & 15, quad = lane >> 4;
  const long hbase = (long)bh << 13;         // (b*8+h)*512*16
  const u16* Qh = QKV + hbase;
  const u16* Kh = QKV + HMSZ + hbase;
  const u16* Vh = QKV + 2 * HMSZ + hbase;
  const long obase = ((long)b * SS) * DD + h * 16;

  for (int i = t; i < 1024; i += 256) {      // 1024 int4 = 512 rows x 16
    int row = i >> 1, half = i & 1;
    *(int4*)&Ks[row * 24 + half * 8] = *(const int4*)&Kh[i * 8];
    u16 v8[8];
    *(int4*)v8 = *(const int4*)&Vh[i * 8];
#pragma unroll
    for (int jj = 0; jj < 8; jj++) Vt[(half * 8 + jj) * 520 + row] = v8[jj];
  }
  __syncthreads();

  const float scale = 0.25f;   // 1/sqrt(16)
  for (int qt = w; qt < 32; qt += 4) {
    const int q0 = qt * 16;
    bf16x8 qf = {0, 0, 0, 0, 0, 0, 0, 0};
    if (quad < 2)
      qf = *(const bf16x8*)&Qh[(q0 + m) * 16 + quad * 8];
    f32x4 oacc = {0.f, 0.f, 0.f, 0.f};
    float mrun[4] = {-1e30f, -1e30f, -1e30f, -1e30f};
    float lrun[4] = {0.f, 0.f, 0.f, 0.f};

    for (int kt = 0; kt < 16; kt++) {
      const int k0 = kt * 32;
      bf16x8 kf0 = {0, 0, 0, 0, 0, 0, 0, 0};
      bf16x8 kf1 = {0, 0, 0, 0, 0, 0, 0, 0};
      if (quad < 2) {
        kf0 = *(const bf16x8*)&Ks[(k0 + m) * 24 + quad * 8];
        kf1 = *(const bf16x8*)&Ks[(k0 + 16 + m) * 24 + quad * 8];
      }
      f32x4 z4 = {0.f, 0.f, 0.f, 0.f};
      f32x4 slo = __builtin_amdgcn_mfma_f32_16x16x32_bf16(qf, kf0, z4, 0, 0, 0);
      f32x4 shi = __builtin_amdgcn_mfma_f32_16x16x32_bf16(qf, kf1, z4, 0, 0, 0);
      u16* pb = &Pb[w][0];
#pragma unroll
      for (int r = 0; r < 4; r++) {
        float sl = slo[r] * scale, sh = shi[r] * scale;
        float mx = fmaxf(sl, sh);
        mx = fmaxf(mx, __shfl_xor(mx, 1));
        mx = fmaxf(mx, __shfl_xor(mx, 2));
        mx = fmaxf(mx, __shfl_xor(mx, 4));
        mx = fmaxf(mx, __shfl_xor(mx, 8));
        float nm = fmaxf(mrun[r], mx);
        float alpha = __expf(mrun[r] - nm);
        mrun[r] = nm;
        float pl = __expf(sl - nm), ph = __expf(sh - nm);
        float rs = pl + ph;
        rs += __shfl_xor(rs, 1);
        rs += __shfl_xor(rs, 2);
        rs += __shfl_xor(rs, 4);
        rs += __shfl_xor(rs, 8);
        lrun[r] = lrun[r] * alpha + rs;
        oacc[r] *= alpha;
        int prow = quad * 4 + r;
        pb[prow * 40 + m] = f2b(pl);
        pb[prow * 40 + 16 + m] = f2b(ph);
      }
      __builtin_amdgcn_s_waitcnt(0xC07F);   // lgkmcnt(0)
      bf16x8 pf = *(const bf16x8*)&pb[m * 40 + quad * 8];
      bf16x8 vf = *(const bf16x8*)&Vt[m * 520 + k0 + quad * 8];
      oacc = __builtin_amdgcn_mfma_f32_16x16x32_bf16(pf, vf, oacc, 0, 0, 0);
    }

#pragma unroll
    for (int r = 0; r < 4; r++) {
      float inv = __fdividef(1.f, lrun[r]);
      Og[obase + (long)(q0 + quad * 4 + r) * DD + m] = f2b(oacc[r] * inv);
    }
  }
}

// ---------------------------------------------------------------------------
__global__ __launch_bounds__(128) void pool_kernel(const float* __restrict__ X,
                                                   float* __restrict__ P) {
  const int b = blockIdx.x, c = threadIdx.x;
  float acc = 0.f;
  for (int s = 0; s < SS; s++) acc += X[((long)b * SS + s) * DD + c];
  P[b * DD + c] = acc * (1.f / 512.f);
}

__global__ __launch_bounds__(64) void cls_kernel(
    const float* __restrict__ P, const float* __restrict__ W1,
    const float* __restrict__ b1, const float* __restrict__ W2,
    const float* __restrict__ b2, float* __restrict__ L) {
  const int b = blockIdx.x, t = threadIdx.x;
  __shared__ float sp[128];
  __shared__ float sh[64];
  sp[t] = P[b * DD + t];
  sp[t + 64] = P[b * DD + 64 + t];
  __syncthreads();
  float acc = b1[t];
  for (int k = 0; k < 128; k++) acc += sp[k] * W1[k * 64 + t];
  sh[t] = fmaxf(acc, 0.f);
  __syncthreads();
  if (t < 5) {
    float acc2 = b2[t];
    for (int k = 0; k < 64; k++) acc2 += sh[k] * W2[k * 5 + t];
    L[b * 5 + t] = acc2;
  }
}

// ---------------------------------------------------------------------------
extern "C" void kernel_launch(void* const* d_in, const int* in_sizes, int n_in,
                              void* d_out, int out_size, void* d_ws, size_t ws_size,
                              hipStream_t stream) {
  const float* ts    = (const float*)d_in[0];
  const float* noise = (const float*)d_in[2];
  const float* dW1   = (const float*)d_in[3];
  const float* db1   = (const float*)d_in[4];
  const float* dW2   = (const float*)d_in[5];
  const float* db2   = (const float*)d_in[6];
  const float* dW3   = (const float*)d_in[7];
  const float* db3   = (const float*)d_in[8];
  const float* gW1   = (const float*)d_in[9];
  const float* gb1   = (const float*)d_in[10];
  const float* gW2   = (const float*)d_in[11];
  const float* gb2   = (const float*)d_in[12];
  const float* mind  = (const float*)d_in[13];
  const float* maxd  = (const float*)d_in[14];
  const float* in_W  = (const float*)d_in[15];
  const float* in_b  = (const float*)d_in[16];
  const float* Wq    = (const float*)d_in[17];
  const float* bq    = (const float*)d_in[18];
  const float* Wk    = (const float*)d_in[19];
  const float* bk    = (const float*)d_in[20];
  const float* Wv    = (const float*)d_in[21];
  const float* bv    = (const float*)d_in[22];
  const float* Wo    = (const float*)d_in[23];
  const float* bo    = (const float*)d_in[24];
  const float* ln1s  = (const float*)d_in[25];
  const float* ln1b  = (const float*)d_in[26];
  const float* fW1   = (const float*)d_in[27];
  const float* fb1   = (const float*)d_in[28];
  const float* fW2   = (const float*)d_in[29];
  const float* fb2   = (const float*)d_in[30];
  const float* ln2s  = (const float*)d_in[31];
  const float* ln2b  = (const float*)d_in[32];
  const float* cW1   = (const float*)d_in[33];
  const float* cb1   = (const float*)d_in[34];
  const float* cW2   = (const float*)d_in[35];
  const float* cb2   = (const float*)d_in[36];

  float* logits = (float*)d_out;
  float* sde    = logits + BB * 5;

  // Workspace layout:
  char* W = (char*)d_ws;
  float* bx    = (float*)(W);                 // 16 MB fp32 x
  u16*  bxb    = (u16*)(W + (16u << 20));     //  8 MB bf16 x
  u16*  bqkvb  = (u16*)(W + (24u << 20));     // 24 MB head-major Q|K|V
  u16*  bh     = (u16*)(W + (24u << 20));     // 32 MB FFN hidden (alias)
  u16*  bob    = (u16*)(W + (56u << 20));     //  8 MB bf16 attn out
  u16*  bsb    = (u16*)(W + (64u << 20));     //  4 MB bf16 sde feats
  u16*  wts    = (u16*)(W + (68u << 20));     // ~1.5 MB bf16 weights
  float* bqkv_bias = (float*)(W + (70u << 20));  // 6 KB
  float* bp    = bqkv_bias + 4 * 384;         // pooled 64x128

  u16* inWt  = wts;                 // [128][64]
  u16* qkvWt = inWt + 8192;         // [4][3][128][128]
  u16* Wot   = qkvWt + 196608;      // [4][128][128]
  u16* fW1t  = Wot + 65536;         // [4][512][128]
  u16* fW2t  = fW1t + 262144;       // [4][128][512]

  prep_weights<<<dim3(64, 4, 7), 256, 0, stream>>>(in_W, Wq, Wk, Wv, Wo, fW1, fW2,
                                                   inWt, qkvWt, Wot, fW1t, fW2t);
  prep_bias<<<4, 384, 0, stream>>>(bq, bk, bv, bqkv_bias);

  sde_kernel<<<64, 512, 0, stream>>>(ts, noise, dW1, db1, dW2, db2, dW3, db3,
                                     gW1, gb1, gW2, gb2, mind, maxd, sde, bsb);

  // x = sde @ in_W + in_b  (dual fp32+bf16 output)
  mfma_gemm<2><<<dim3(2, 256), 256, 0, stream>>>(bsb, inWt, in_b, bx, bxb, 64, 128);

  for (int l = 0; l < 4; l++) {
    // fused QKV GEMM -> head-major Q/K/V
    mfma_gemm<4><<<dim3(6, 256), 256, 0, stream>>>(bxb, qkvWt + l * 49152,
                                                   bqkv_bias + l * 384, nullptr,
                                                   bqkvb, 128, 384);
    attn_mfma<<<BB * NHD, 256, 0, stream>>>(bqkvb, bob);
    // O-projection + residual + LN1 (fused)
    gemm_ln<<<256, 256, 0, stream>>>(bob, Wot + l * 16384, bo + l * DD, bx,
                                     ln1s + l * DD, ln1b + l * DD, bx, bxb, 128);
    // FFN1 (relu, bf16 out)
    mfma_gemm<1><<<dim3(8, 256), 256, 0, stream>>>(bxb, fW1t + l * 65536,
                                                   fb1 + l * 512, nullptr, bh, 128, 512);
    // FFN2 + residual + LN2 (fused)
    gemm_ln<<<256, 256, 0, stream>>>(bh, fW2t + l * 65536, fb2 + l * DD, bx,
                                     ln2s + l * DD, ln2b + l * DD, bx, bxb, 512);
  }

  pool_kernel<<<BB, 128, 0, stream>>>(bx, bp);
  cls_kernel<<<BB, 64, 0, stream>>>(bp, cW1, cb1, cW2, cb2, logits);
}

// Round 8
// 1352.026 us; speedup vs baseline: 1.5204x; 1.1554x over previous
//
#include <hip/hip_runtime.h>
#include <hip/hip_bf16.h>
#include <math.h>

#define BB 64
#define SS 512
#define HH 64
#define DD 128
#define NHD 8
#define ROWS (BB*SS)   // 32768
#define HMSZ 4194304   // u16 elems per head-major Q/K/V buffer (64*8*512*16)

typedef unsigned short u16;
typedef __attribute__((ext_vector_type(8))) short bf16x8;
typedef __attribute__((ext_vector_type(4))) float f32x4;

__device__ __forceinline__ u16 f2b(float f) {
  union { float f; unsigned u; } x; x.f = f;
  unsigned r = x.u + 0x7fffu + ((x.u >> 16) & 1u);
  return (u16)(r >> 16);
}

__device__ __forceinline__ float b2f(u16 u) {
  return __uint_as_float(((unsigned)u) << 16);
}

__device__ __forceinline__ float fast_tanh(float x) {
  float ax = fminf(fabsf(x), 15.f);
  float e = __expf(2.f * ax);
  float r = 1.f - __fdividef(2.f, e + 1.f);
  return copysignf(r, x);
}

__device__ __forceinline__ void barrier_lds() {
  __builtin_amdgcn_s_waitcnt(0xC07F);   // lgkmcnt(0) only
  __builtin_amdgcn_s_barrier();
}

// ---------------------------------------------------------------------------
// SDE scan v7: 512 thr. Stage A now pairs (drift[c], gate[c]) per lane with
// 4-way K-split — shared y-window halves stage-A LDS reads (8 -> 4 b128).
// ---------------------------------------------------------------------------
__global__ __launch_bounds__(512, 2) void sde_kernel(
    const float* __restrict__ ts, const float* __restrict__ noise,
    const float* __restrict__ dW1, const float* __restrict__ db1,
    const float* __restrict__ dW2, const float* __restrict__ db2,
    const float* __restrict__ dW3, const float* __restrict__ db3,
    const float* __restrict__ gW1, const float* __restrict__ gb1,
    const float* __restrict__ gW2, const float* __restrict__ gb2,
    const float* __restrict__ pmind, const float* __restrict__ pmaxd,
    float* __restrict__ out, u16* __restrict__ outB) {
  const int b = blockIdx.x, t = threadIdx.x;
  __shared__ float y_s[64];
  __shared__ float h1g1[256];
  __shared__ float h2s[64], gcs[64];
  __shared__ float tl_s[512], hs_s[512], sq_s[512];

  const float mind = fabsf(pmind[0]);
  const float maxd = fabsf(pmaxd[0]);

  // stage A: col pair cA (0..127), 4-way k-split qA
  const int cA = t >> 2, qA = t & 3;
  float wAd[16], wAg[16];
#pragma unroll
  for (int k = 0; k < 16; k++) {
    wAd[k] = dW1[(qA * 16 + k) * 128 + cA];
    wAg[k] = gW1[(qA * 16 + k) * 128 + cA];
  }
  const float wAtd = dW1[64 * 128 + cA], wAtg = gW1[64 * 128 + cA];
  const float bAd = db1[cA], bAg = gb1[cA];

  // stage B: output oB (0..127: h2 then gc), 4-way k-split qB
  const int oB = t >> 2, qB = t & 3;
  const int cB = oB & 63;
  const float* W2 = (oB < 64) ? dW2 : gW2;
  float wB[32];
#pragma unroll
  for (int k = 0; k < 32; k++) wB[k] = W2[(qB * 32 + k) * 64 + cB];
  const float bB = ((oB < 64) ? db2 : gb2)[cB];

  // stage C: output cC (0..63), 8-way k-split qC
  const int cC = t >> 3, qC = t & 7;
  float wC[8];
#pragma unroll
  for (int k = 0; k < 8; k++) wC[k] = dW3[(qC * 8 + k) * 64 + cC];
  const float bC = db3[cC];

  // prologue
  tl_s[t] = ts[t * 3];
  __syncthreads();
  if (t < 511) {
    float hh = tl_s[t + 1] - tl_s[t];
    hs_s[t] = hh;
    sq_s[t] = sqrtf(hh);
  }
  if (t < 64) {
    float y = 0.1f;
    if (t < 3) y = fminf(fmaxf(ts[b * 1536 + t], 0.01f), 10.f);
    y_s[t] = y;
    out[(long)b * 32768 + t] = y;
    outB[((long)b * 512) * 64 + t] = f2b(y);
  }
  float nz = noise[b * 64 + cC];
  __syncthreads();

  for (int i = 0; i < 511; i++) {
    float nzn = 0.f;
    if (i < 510) nzn = noise[(long)(i + 1) * 4096 + b * 64 + cC];
    const float tl = tl_s[i];
    const float hh = hs_s[i];
    const float sq = sq_s[i];

    // ---- stage A: drift+gate layer1, shared y window (4 b128 reads) ----
    float ad0 = 0.f, ad1 = 0.f, ag0 = 0.f, ag1 = 0.f;
#pragma unroll
    for (int g = 0; g < 4; g++) {
      float4 yv = *(const float4*)&y_s[qA * 16 + g * 4];
      ad0 += yv.x * wAd[g * 4 + 0] + yv.y * wAd[g * 4 + 1];
      ad1 += yv.z * wAd[g * 4 + 2] + yv.w * wAd[g * 4 + 3];
      ag0 += yv.x * wAg[g * 4 + 0] + yv.y * wAg[g * 4 + 1];
      ag1 += yv.z * wAg[g * 4 + 2] + yv.w * wAg[g * 4 + 3];
    }
    float ad = ad0 + ad1, ag = ag0 + ag1;
    if (qA == 0) { ad += tl * wAtd; ag += tl * wAtg; }
    ad += __shfl_xor(ad, 1); ad += __shfl_xor(ad, 2);
    ag += __shfl_xor(ag, 1); ag += __shfl_xor(ag, 2);
    if (qA == 0) {
      h1g1[cA] = fast_tanh(ad + bAd);
      h1g1[128 + cA] = fast_tanh(ag + bAg);
    }
    barrier_lds();                        // barrier 1

    // ---- stage B ----
    const float* srcB = h1g1 + ((oB < 64) ? 0 : 128) + qB * 32;
    float c0 = 0.f, c1 = 0.f, c2 = 0.f, c3 = 0.f;
#pragma unroll
    for (int g = 0; g < 8; g++) {
      float4 xv = *(const float4*)&srcB[g * 4];
      c0 += xv.x * wB[g * 4 + 0];
      c1 += xv.y * wB[g * 4 + 1];
      c2 += xv.z * wB[g * 4 + 2];
      c3 += xv.w * wB[g * 4 + 3];
    }
    float p2 = (c0 + c1) + (c2 + c3);
    p2 += __shfl_xor(p2, 1);
    p2 += __shfl_xor(p2, 2);
    if (qB == 0) {
      p2 += bB;
      if (oB < 64) {
        h2s[cB] = fast_tanh(p2);
      } else {
        gcs[cB] = fmaxf(p2, 0.f) + __logf(1.f + __expf(-fabsf(p2))) + mind;
      }
    }
    barrier_lds();                        // barrier 2

    // ---- stage C ----
    float d0 = 0.f, d1 = 0.f;
#pragma unroll
    for (int g = 0; g < 2; g++) {
      float4 hv = *(const float4*)&h2s[qC * 8 + g * 4];
      d0 += hv.x * wC[g * 4 + 0];
      d0 += hv.y * wC[g * 4 + 1];
      d1 += hv.z * wC[g * 4 + 2];
      d1 += hv.w * wC[g * 4 + 3];
    }
    float p3 = d0 + d1;
    p3 += __shfl_xor(p3, 1);
    p3 += __shfl_xor(p3, 2);
    p3 += __shfl_xor(p3, 4);
    if (qC == 0) {
      float dc = fminf(fmaxf(p3 + bC, -maxd), maxd);
      float yo = y_s[cC];
      float gg = gcs[cC] * fminf(fmaxf(yo, -10.f), 10.f);
      float yn = yo + dc * yo * hh + gg * nz * sq;
      yn = fminf(fmaxf(yn, 0.01f), 10.f);
      y_s[cC] = yn;
      out[(long)b * 32768 + (i + 1) * 64 + cC] = yn;
      outB[((long)b * 512 + i + 1) * 64 + cC] = f2b(yn);
    }
    nz = nzn;
    barrier_lds();                        // barrier 3
  }
}

// ---------------------------------------------------------------------------
__global__ __launch_bounds__(256) void prep_weights(
    const float* __restrict__ in_W, const float* __restrict__ Wq,
    const float* __restrict__ Wk, const float* __restrict__ Wv,
    const float* __restrict__ Wo, const float* __restrict__ fW1,
    const float* __restrict__ fW2,
    u16* __restrict__ inWt, u16* __restrict__ qkvWt, u16* __restrict__ Wot,
    u16* __restrict__ fW1t, u16* __restrict__ fW2t) {
  const int z = blockIdx.z, layer = blockIdx.y, tile = blockIdx.x;
  const float* src; u16* dst; int R, C, nl;
  switch (z) {
    case 0: src = in_W; dst = inWt; R = 64; C = 128; nl = 1; break;
    case 1: src = Wq + layer * 16384; dst = qkvWt + layer * 49152; R = 128; C = 128; nl = 4; break;
    case 2: src = Wk + layer * 16384; dst = qkvWt + layer * 49152 + 16384; R = 128; C = 128; nl = 4; break;
    case 3: src = Wv + layer * 16384; dst = qkvWt + layer * 49152 + 32768; R = 128; C = 128; nl = 4; break;
    case 4: src = Wo + layer * 16384; dst = Wot + layer * 16384; R = 128; C = 128; nl = 4; break;
    case 5: src = fW1 + layer * 65536; dst = fW1t + layer * 65536; R = 128; C = 512; nl = 4; break;
    default: src = fW2 + layer * 65536; dst = fW2t + layer * 65536; R = 512; C = 128; nl = 4; break;
  }
  const int nt = (R / 32) * (C / 32);
  if (layer >= nl || tile >= nt) return;
  const int tpr = C / 32;
  const int r0 = (tile / tpr) * 32, c0 = (tile % tpr) * 32;
  __shared__ float tl[32][33];
  const int tx = threadIdx.x & 31, ty = threadIdx.x >> 5;
#pragma unroll
  for (int p = 0; p < 4; p++)
    tl[ty + 8 * p][tx] = src[(long)(r0 + ty + 8 * p) * C + c0 + tx];
  __syncthreads();
#pragma unroll
  for (int p = 0; p < 4; p++)
    dst[(long)(c0 + ty + 8 * p) * R + r0 + tx] = f2b(tl[tx][ty + 8 * p]);
}

__global__ __launch_bounds__(384) void prep_bias(
    const float* __restrict__ bq, const float* __restrict__ bk,
    const float* __restrict__ bv, float* __restrict__ bqkv) {
  const int l = blockIdx.x, c = threadIdx.x;
  float v;
  if (c < 128) v = bq[l * 128 + c];
  else if (c < 256) v = bk[l * 128 + c - 128];
  else v = bv[l * 128 + c - 256];
  bqkv[l * 384 + c] = v;
}

// ---------------------------------------------------------------------------
// bf16 MFMA GEMM. MODE 1: bf16+relu. MODE 3: bf16. MODE 4: head-major scatter.
// ---------------------------------------------------------------------------
template <int MODE>
__global__ __launch_bounds__(256) void mfma_gemm(
    const u16* __restrict__ A, const u16* __restrict__ Bt,
    const float* __restrict__ bias, u16* __restrict__ outB, int K, int N) {
  __shared__ u16 As[128 * 40];
  __shared__ u16 Bs[64 * 40];
  const int t = threadIdx.x;
  const int nb = blockIdx.x * 64;
  const long mb = (long)blockIdx.y * 128;
  const int lane = t & 63, wave = t >> 6;
  const int wm = (wave >> 1) * 64, wn = (wave & 1) * 32;
  const int fr = lane & 15, quad = lane >> 4;

  f32x4 zero = {0.f, 0.f, 0.f, 0.f};
  f32x4 acc[4][2];
#pragma unroll
  for (int mi = 0; mi < 4; mi++)
#pragma unroll
    for (int ni = 0; ni < 2; ni++) acc[mi][ni] = zero;

  for (int k0 = 0; k0 < K; k0 += 32) {
#pragma unroll
    for (int p = 0; p < 2; p++) {
      int idx = t + p * 256, row = idx >> 2, seg = idx & 3;
      int4 v = *(const int4*)&A[(mb + row) * K + k0 + seg * 8];
      *(int4*)&As[row * 40 + seg * 8] = v;
    }
    {
      int row = t >> 2, seg = t & 3;
      int4 v = *(const int4*)&Bt[(long)(nb + row) * K + k0 + seg * 8];
      *(int4*)&Bs[row * 40 + seg * 8] = v;
    }
    __syncthreads();
    bf16x8 af[4], bfr[2];
#pragma unroll
    for (int mi = 0; mi < 4; mi++)
      af[mi] = *(const bf16x8*)&As[(wm + mi * 16 + fr) * 40 + quad * 8];
#pragma unroll
    for (int ni = 0; ni < 2; ni++)
      bfr[ni] = *(const bf16x8*)&Bs[(wn + ni * 16 + fr) * 40 + quad * 8];
#pragma unroll
    for (int mi = 0; mi < 4; mi++)
#pragma unroll
      for (int ni = 0; ni < 2; ni++)
        acc[mi][ni] = __builtin_amdgcn_mfma_f32_16x16x32_bf16(
            af[mi], bfr[ni], acc[mi][ni], 0, 0, 0);
    __syncthreads();
  }

#pragma unroll
  for (int mi = 0; mi < 4; mi++)
#pragma unroll
    for (int ni = 0; ni < 2; ni++) {
      int col = nb + wn + ni * 16 + fr;
      float bv = bias[col];
#pragma unroll
      for (int r = 0; r < 4; r++) {
        long row = mb + wm + mi * 16 + quad * 4 + r;
        float v = acc[mi][ni][r] + bv;
        if (MODE == 1) {
          outB[row * N + col] = f2b(fmaxf(v, 0.f));
        } else if (MODE == 3) {
          outB[row * N + col] = f2b(v);
        } else {
          int which = col >> 7, h = (col >> 4) & 7, d = col & 15;
          long bidx = row >> 9, s = row & 511;
          outB[(long)which * HMSZ + (((bidx << 3) + h) << 13) + (s << 4) + d] =
              f2b(v);
        }
      }
    }
}

// ---------------------------------------------------------------------------
// Fused GEMM + residual(bf16) + LayerNorm -> bf16. Tile 64x128, 512 blocks.
// ---------------------------------------------------------------------------
__global__ __launch_bounds__(256) void gemm_ln(
    const u16* __restrict__ A, const u16* __restrict__ Bt,
    const float* __restrict__ bias, const u16* __restrict__ resid,
    const float* __restrict__ gamma, const float* __restrict__ beta,
    u16* __restrict__ outB, int K) {
  __shared__ u16 As[64 * 40];
  __shared__ u16 Bs[128 * 40];
  __shared__ float s1[2][64], s2[2][64];
  const int t = threadIdx.x;
  const long mb = (long)blockIdx.x * 64;
  const int lane = t & 63, wave = t >> 6;
  const int wm = (wave >> 1) * 32, wn = (wave & 1) * 64;
  const int fr = lane & 15, quad = lane >> 4;

  f32x4 zero = {0.f, 0.f, 0.f, 0.f};
  f32x4 acc[2][4];
#pragma unroll
  for (int mi = 0; mi < 2; mi++)
#pragma unroll
    for (int ni = 0; ni < 4; ni++) acc[mi][ni] = zero;

  for (int k0 = 0; k0 < K; k0 += 32) {
    {
      int row = t >> 2, seg = t & 3;
      *(int4*)&As[row * 40 + seg * 8] =
          *(const int4*)&A[(mb + row) * K + k0 + seg * 8];
    }
#pragma unroll
    for (int p = 0; p < 2; p++) {
      int idx = t + p * 256, row = idx >> 2, seg = idx & 3;
      *(int4*)&Bs[row * 40 + seg * 8] =
          *(const int4*)&Bt[(long)row * K + k0 + seg * 8];
    }
    __syncthreads();
    bf16x8 af[2], bfr[4];
#pragma unroll
    for (int mi = 0; mi < 2; mi++)
      af[mi] = *(const bf16x8*)&As[(wm + mi * 16 + fr) * 40 + quad * 8];
#pragma unroll
    for (int ni = 0; ni < 4; ni++)
      bfr[ni] = *(const bf16x8*)&Bs[(wn + ni * 16 + fr) * 40 + quad * 8];
#pragma unroll
    for (int mi = 0; mi < 2; mi++)
#pragma unroll
      for (int ni = 0; ni < 4; ni++)
        acc[mi][ni] = __builtin_amdgcn_mfma_f32_16x16x32_bf16(
            af[mi], bfr[ni], acc[mi][ni], 0, 0, 0);
    __syncthreads();
  }

  float bv[4], gv[4], be[4];
#pragma unroll
  for (int ni = 0; ni < 4; ni++) {
    int col = wn + ni * 16 + fr;
    bv[ni] = bias[col];
    gv[ni] = gamma[col];
    be[ni] = beta[col];
  }

#pragma unroll
  for (int mi = 0; mi < 2; mi++) {
#pragma unroll
    for (int r = 0; r < 4; r++) {
      int rloc = wm + mi * 16 + quad * 4 + r;
      long row = mb + rloc;
      float s = 0.f, ss = 0.f;
#pragma unroll
      for (int ni = 0; ni < 4; ni++) {
        int col = wn + ni * 16 + fr;
        float v = acc[mi][ni][r] + bv[ni] + b2f(resid[row * DD + col]);
        acc[mi][ni][r] = v;
        s += v;
        ss += v * v;
      }
      s += __shfl_xor(s, 1); ss += __shfl_xor(ss, 1);
      s += __shfl_xor(s, 2); ss += __shfl_xor(ss, 2);
      s += __shfl_xor(s, 4); ss += __shfl_xor(ss, 4);
      s += __shfl_xor(s, 8); ss += __shfl_xor(ss, 8);
      if (fr == 0) {
        s1[wn >> 6][rloc] = s;
        s2[wn >> 6][rloc] = ss;
      }
    }
  }
  __syncthreads();

#pragma unroll
  for (int mi = 0; mi < 2; mi++) {
#pragma unroll
    for (int r = 0; r < 4; r++) {
      int rloc = wm + mi * 16 + quad * 4 + r;
      long row = mb + rloc;
      float sum = s1[0][rloc] + s1[1][rloc];
      float sumsq = s2[0][rloc] + s2[1][rloc];
      float mean = sum * (1.f / 128.f);
      float var = sumsq * (1.f / 128.f) - mean * mean;
      float rstd = rsqrtf(var + 1e-5f);
#pragma unroll
      for (int ni = 0; ni < 4; ni++) {
        int col = wn + ni * 16 + fr;
        float o = (acc[mi][ni][r] - mean) * rstd * gv[ni] + be[ni];
        outB[row * DD + col] = f2b(o);
      }
    }
  }
}

// ---------------------------------------------------------------------------
// Flash attention v2: S^T orientation. A=K rows, B=Q rows -> lane owns one
// query column; softmax state per-lane (no per-row shuffle storms, no LDS
// P round-trip/drain). P transpose via 8 ds_bpermute. PV: O^T = V^T @ P^T.
// ---------------------------------------------------------------------------
__global__ __launch_bounds__(256, 2) void attn_mfma(
    const u16* __restrict__ QKV, u16* __restrict__ Og) {
  const int bh = blockIdx.x;
  const int b = bh >> 3, h = bh & 7;
  __shared__ u16 Ks[512 * 24];
  __shared__ u16 Vt[16 * 520];
  const int t = threadIdx.x;
  const int w = t >> 6, lane = t & 63;
  const int fr = lane & 15, quad = lane >> 4;
  const long hbase = (long)bh << 13;
  const u16* Qh = QKV + hbase;
  const u16* Kh = QKV + HMSZ + hbase;
  const u16* Vh = QKV + 2 * HMSZ + hbase;
  const long obase = ((long)b * SS) * DD + h * 16;

  for (int i = t; i < 1024; i += 256) {
    int row = i >> 1, half = i & 1;
    *(int4*)&Ks[row * 24 + half * 8] = *(const int4*)&Kh[i * 8];
    u16 v8[8];
    *(int4*)v8 = *(const int4*)&Vh[i * 8];
#pragma unroll
    for (int jj = 0; jj < 8; jj++) Vt[(half * 8 + jj) * 520 + row] = v8[jj];
  }
  __syncthreads();

  const float scale = 0.25f;                 // 1/sqrt(16)
  const int addrA = (((quad & 1) * 32) + fr) * 4;  // byte addr for bpermute
  const int addrB = addrA + 64;                    // +16 lanes
  const bool loTile = (quad < 2);
  const f32x4 z4 = {0.f, 0.f, 0.f, 0.f};

  for (int qt = w; qt < 32; qt += 4) {
    const int q0 = qt * 16;
    bf16x8 qf = {0, 0, 0, 0, 0, 0, 0, 0};
    if (quad < 2)
      qf = *(const bf16x8*)&Qh[(q0 + fr) * 16 + quad * 8];
    f32x4 oacc = {0.f, 0.f, 0.f, 0.f};
    float mrun = -1e30f, lrun = 0.f;

    for (int kt = 0; kt < 16; kt++) {
      const int k0 = kt * 32;
      bf16x8 kf0 = {0, 0, 0, 0, 0, 0, 0, 0};
      bf16x8 kf1 = {0, 0, 0, 0, 0, 0, 0, 0};
      if (quad < 2) {
        kf0 = *(const bf16x8*)&Ks[(k0 + fr) * 24 + quad * 8];
        kf1 = *(const bf16x8*)&Ks[(k0 + 16 + fr) * 24 + quad * 8];
      }
      // S^T[key][q]: lane holds keys quad*4+r (lo) / 16+quad*4+r (hi), q=fr
      f32x4 slo = __builtin_amdgcn_mfma_f32_16x16x32_bf16(kf0, qf, z4, 0, 0, 0);
      f32x4 shi = __builtin_amdgcn_mfma_f32_16x16x32_bf16(kf1, qf, z4, 0, 0, 0);
      float s[8];
#pragma unroll
      for (int r = 0; r < 4; r++) {
        s[r] = slo[r] * scale;
        s[4 + r] = shi[r] * scale;
      }
      float mx = s[0];
#pragma unroll
      for (int r = 1; r < 8; r++) mx = fmaxf(mx, s[r]);
      mx = fmaxf(mx, __shfl_xor(mx, 16));
      mx = fmaxf(mx, __shfl_xor(mx, 32));
      float nm = fmaxf(mrun, mx);
      float alpha = __expf(mrun - nm);
      mrun = nm;
      float p[8], rs = 0.f;
#pragma unroll
      for (int r = 0; r < 8; r++) {
        p[r] = __expf(s[r] - nm);
        rs += p[r];
      }
      rs += __shfl_xor(rs, 16);
      rs += __shfl_xor(rs, 32);
      lrun = lrun * alpha + rs;
#pragma unroll
      for (int r = 0; r < 4; r++) oacc[r] *= alpha;

      // pack P pairs (bf16x2): lo tile pk0/pk1, hi tile pk2/pk3
      int pk0 = ((int)f2b(p[1]) << 16) | f2b(p[0]);
      int pk1 = ((int)f2b(p[3]) << 16) | f2b(p[2]);
      int pk2 = ((int)f2b(p[5]) << 16) | f2b(p[4]);
      int pk3 = ((int)f2b(p[7]) << 16) | f2b(p[6]);
      // assemble B-frag of P^T: target lane (q=fr, quad) needs keys quad*8+0..7
      int B0a = __builtin_amdgcn_ds_bpermute(addrA, pk0);
      int B0b = __builtin_amdgcn_ds_bpermute(addrA, pk2);
      int B1a = __builtin_amdgcn_ds_bpermute(addrA, pk1);
      int B1b = __builtin_amdgcn_ds_bpermute(addrA, pk3);
      int B2a = __builtin_amdgcn_ds_bpermute(addrB, pk0);
      int B2b = __builtin_amdgcn_ds_bpermute(addrB, pk2);
      int B3a = __builtin_amdgcn_ds_bpermute(addrB, pk1);
      int B3b = __builtin_amdgcn_ds_bpermute(addrB, pk3);
      union { int i[4]; bf16x8 v; } pu;
      pu.i[0] = loTile ? B0a : B0b;
      pu.i[1] = loTile ? B1a : B1b;
      pu.i[2] = loTile ? B2a : B2b;
      pu.i[3] = loTile ? B3a : B3b;
      bf16x8 vf = *(const bf16x8*)&Vt[fr * 520 + k0 + quad * 8];
      // O^T[d][q] += V^T[d][key] * P^T[key][q]
      oacc = __builtin_amdgcn_mfma_f32_16x16x32_bf16(vf, pu.v, oacc, 0, 0, 0);
    }

    float inv = __fdividef(1.f, lrun);
    ushort4 o;
    o.x = f2b(oacc[0] * inv);
    o.y = f2b(oacc[1] * inv);
    o.z = f2b(oacc[2] * inv);
    o.w = f2b(oacc[3] * inv);
    *(ushort4*)&Og[obase + (long)(q0 + fr) * DD + quad * 4] = o;
  }
}

// ---------------------------------------------------------------------------
__global__ __launch_bounds__(128) void pool_kernel(const u16* __restrict__ X,
                                                   float* __restrict__ P) {
  const int b = blockIdx.x, c = threadIdx.x;
  float acc = 0.f;
  for (int s = 0; s < SS; s++) acc += b2f(X[((long)b * SS + s) * DD + c]);
  P[b * DD + c] = acc * (1.f / 512.f);
}

__global__ __launch_bounds__(64) void cls_kernel(
    const float* __restrict__ P, const float* __restrict__ W1,
    const float* __restrict__ b1, const float* __restrict__ W2,
    const float* __restrict__ b2, float* __restrict__ L) {
  const int b = blockIdx.x, t = threadIdx.x;
  __shared__ float sp[128];
  __shared__ float sh[64];
  sp[t] = P[b * DD + t];
  sp[t + 64] = P[b * DD + 64 + t];
  __syncthreads();
  float acc = b1[t];
  for (int k = 0; k < 128; k++) acc += sp[k] * W1[k * 64 + t];
  sh[t] = fmaxf(acc, 0.f);
  __syncthreads();
  if (t < 5) {
    float acc2 = b2[t];
    for (int k = 0; k < 64; k++) acc2 += sh[k] * W2[k * 5 + t];
    L[b * 5 + t] = acc2;
  }
}

// ---------------------------------------------------------------------------
extern "C" void kernel_launch(void* const* d_in, const int* in_sizes, int n_in,
                              void* d_out, int out_size, void* d_ws, size_t ws_size,
                              hipStream_t stream) {
  const float* ts    = (const float*)d_in[0];
  const float* noise = (const float*)d_in[2];
  const float* dW1   = (const float*)d_in[3];
  const float* db1   = (const float*)d_in[4];
  const float* dW2   = (const float*)d_in[5];
  const float* db2   = (const float*)d_in[6];
  const float* dW3   = (const float*)d_in[7];
  const float* db3   = (const float*)d_in[8];
  const float* gW1   = (const float*)d_in[9];
  const float* gb1   = (const float*)d_in[10];
  const float* gW2   = (const float*)d_in[11];
  const float* gb2   = (const float*)d_in[12];
  const float* mind  = (const float*)d_in[13];
  const float* maxd  = (const float*)d_in[14];
  const float* in_W  = (const float*)d_in[15];
  const float* in_b  = (const float*)d_in[16];
  const float* Wq    = (const float*)d_in[17];
  const float* bq    = (const float*)d_in[18];
  const float* Wk    = (const float*)d_in[19];
  const float* bk    = (const float*)d_in[20];
  const float* Wv    = (const float*)d_in[21];
  const float* bv    = (const float*)d_in[22];
  const float* Wo    = (const float*)d_in[23];
  const float* bo    = (const float*)d_in[24];
  const float* ln1s  = (const float*)d_in[25];
  const float* ln1b  = (const float*)d_in[26];
  const float* fW1   = (const float*)d_in[27];
  const float* fb1   = (const float*)d_in[28];
  const float* fW2   = (const float*)d_in[29];
  const float* fb2   = (const float*)d_in[30];
  const float* ln2s  = (const float*)d_in[31];
  const float* ln2b  = (const float*)d_in[32];
  const float* cW1   = (const float*)d_in[33];
  const float* cb1   = (const float*)d_in[34];
  const float* cW2   = (const float*)d_in[35];
  const float* cb2   = (const float*)d_in[36];

  float* logits = (float*)d_out;
  float* sde    = logits + BB * 5;

  // Workspace (all-bf16 residual stream):
  char* W = (char*)d_ws;
  u16*  bxb    = (u16*)(W);                   //  8 MB bf16 x (residual stream)
  u16*  bqkvb  = (u16*)(W + (8u << 20));      // 24 MB head-major Q|K|V
  u16*  bh     = (u16*)(W + (8u << 20));      // 32 MB FFN hidden (alias)
  u16*  bob    = (u16*)(W + (40u << 20));     //  8 MB bf16 attn out
  u16*  bsb    = (u16*)(W + (48u << 20));     //  4 MB bf16 sde feats
  u16*  wts    = (u16*)(W + (52u << 20));     // ~1.5 MB bf16 weights
  float* bqkv_bias = (float*)(W + (54u << 20));
  float* bp    = bqkv_bias + 4 * 384;         // pooled 64x128

  u16* inWt  = wts;                 // [128][64]
  u16* qkvWt = inWt + 8192;         // [4][3][128][128]
  u16* Wot   = qkvWt + 196608;      // [4][128][128]
  u16* fW1t  = Wot + 65536;         // [4][512][128]
  u16* fW2t  = fW1t + 262144;       // [4][128][512]

  prep_weights<<<dim3(64, 4, 7), 256, 0, stream>>>(in_W, Wq, Wk, Wv, Wo, fW1, fW2,
                                                   inWt, qkvWt, Wot, fW1t, fW2t);
  prep_bias<<<4, 384, 0, stream>>>(bq, bk, bv, bqkv_bias);

  sde_kernel<<<64, 512, 0, stream>>>(ts, noise, dW1, db1, dW2, db2, dW3, db3,
                                     gW1, gb1, gW2, gb2, mind, maxd, sde, bsb);

  // x = sde @ in_W + in_b  (bf16)
  mfma_gemm<3><<<dim3(2, 256), 256, 0, stream>>>(bsb, inWt, in_b, bxb, 64, 128);

  for (int l = 0; l < 4; l++) {
    mfma_gemm<4><<<dim3(6, 256), 256, 0, stream>>>(bxb, qkvWt + l * 49152,
                                                   bqkv_bias + l * 384, bqkvb, 128, 384);
    attn_mfma<<<BB * NHD, 256, 0, stream>>>(bqkvb, bob);
    gemm_ln<<<512, 256, 0, stream>>>(bob, Wot + l * 16384, bo + l * DD, bxb,
                                     ln1s + l * DD, ln1b + l * DD, bxb, 128);
    mfma_gemm<1><<<dim3(8, 256), 256, 0, stream>>>(bxb, fW1t + l * 65536,
                                                   fb1 + l * 512, bh, 128, 512);
    gemm_ln<<<512, 256, 0, stream>>>(bh, fW2t + l * 65536, fb2 + l * DD, bxb,
                                     ln2s + l * DD, ln2b + l * DD, bxb, 512);
  }

  pool_kernel<<<BB, 128, 0, stream>>>(bxb, bp);
  cls_kernel<<<BB, 64, 0, stream>>>(bp, cW1, cb1, cW2, cb2, logits);
}

// Round 9
// 1261.187 us; speedup vs baseline: 1.6299x; 1.0720x over previous
//
#include <hip/hip_runtime.h>
#include <hip/hip_bf16.h>
#include <math.h>

#define BB 64
#define SS 512
#define HH 64
#define DD 128
#define NHD 8
#define ROWS (BB*SS)   // 32768

typedef unsigned short u16;
typedef __attribute__((ext_vector_type(8))) short bf16x8;
typedef __attribute__((ext_vector_type(4))) float f32x4;

__device__ __forceinline__ u16 f2b(float f) {
  union { float f; unsigned u; } x; x.f = f;
  unsigned r = x.u + 0x7fffu + ((x.u >> 16) & 1u);
  return (u16)(r >> 16);
}

__device__ __forceinline__ float b2f(u16 u) {
  return __uint_as_float(((unsigned)u) << 16);
}

__device__ __forceinline__ float fast_tanh(float x) {
  float ax = fminf(fabsf(x), 15.f);
  float e = __expf(2.f * ax);
  float r = 1.f - __fdividef(2.f, e + 1.f);
  return copysignf(r, x);
}

__device__ __forceinline__ void barrier_lds() {
  __builtin_amdgcn_s_waitcnt(0xC07F);   // lgkmcnt(0) only
  __builtin_amdgcn_s_barrier();
}

// ---------------------------------------------------------------------------
// SDE scan (v6 partition — best measured config, 583 us):
// 512 thr, stage A 2-way split, B 4-way, C 8-way, LDS-only barriers.
// ---------------------------------------------------------------------------
__global__ __launch_bounds__(512, 2) void sde_kernel(
    const float* __restrict__ ts, const float* __restrict__ noise,
    const float* __restrict__ dW1, const float* __restrict__ db1,
    const float* __restrict__ dW2, const float* __restrict__ db2,
    const float* __restrict__ dW3, const float* __restrict__ db3,
    const float* __restrict__ gW1, const float* __restrict__ gb1,
    const float* __restrict__ gW2, const float* __restrict__ gb2,
    const float* __restrict__ pmind, const float* __restrict__ pmaxd,
    float* __restrict__ out, u16* __restrict__ outB) {
  const int b = blockIdx.x, t = threadIdx.x;
  __shared__ float y_s[64];
  __shared__ float h1g1[256];
  __shared__ float h2s[64], gcs[64];
  __shared__ float tl_s[512], hs_s[512], sq_s[512];

  const float mind = fabsf(pmind[0]);
  const float maxd = fabsf(pmaxd[0]);

  const int oA = t >> 1, hA = t & 1;
  const int cA = oA & 127;
  const float* W1 = (oA < 128) ? dW1 : gW1;
  float wA[32];
#pragma unroll
  for (int k = 0; k < 32; k++) wA[k] = W1[(hA * 32 + k) * 128 + cA];
  const float wAt = W1[64 * 128 + cA];
  const float bA = ((oA < 128) ? db1 : gb1)[cA];

  const int oB = t >> 2, qB = t & 3;
  const int cB = oB & 63;
  const float* W2 = (oB < 64) ? dW2 : gW2;
  float wB[32];
#pragma unroll
  for (int k = 0; k < 32; k++) wB[k] = W2[(qB * 32 + k) * 64 + cB];
  const float bB = ((oB < 64) ? db2 : gb2)[cB];

  const int cC = t >> 3, qC = t & 7;
  float wC[8];
#pragma unroll
  for (int k = 0; k < 8; k++) wC[k] = dW3[(qC * 8 + k) * 64 + cC];
  const float bC = db3[cC];

  // prologue
  tl_s[t] = ts[t * 3];
  __syncthreads();
  if (t < 511) {
    float hh = tl_s[t + 1] - tl_s[t];
    hs_s[t] = hh;
    sq_s[t] = sqrtf(hh);
  }
  if (t < 64) {
    float y = 0.1f;
    if (t < 3) y = fminf(fmaxf(ts[b * 1536 + t], 0.01f), 10.f);
    y_s[t] = y;
    out[(long)b * 32768 + t] = y;
    outB[((long)b * 512) * 64 + t] = f2b(y);
  }
  float nz = noise[b * 64 + cC];
  __syncthreads();

  for (int i = 0; i < 511; i++) {
    float nzn = 0.f;
    if (i < 510) nzn = noise[(long)(i + 1) * 4096 + b * 64 + cC];
    const float tl = tl_s[i];
    const float hh = hs_s[i];
    const float sq = sq_s[i];

    // ---- stage A ----
    float a0 = 0.f, a1 = 0.f, a2 = 0.f, a3 = 0.f;
#pragma unroll
    for (int g = 0; g < 8; g++) {
      float4 yv = *(const float4*)&y_s[hA * 32 + g * 4];
      a0 += yv.x * wA[g * 4 + 0];
      a1 += yv.y * wA[g * 4 + 1];
      a2 += yv.z * wA[g * 4 + 2];
      a3 += yv.w * wA[g * 4 + 3];
    }
    float p1 = (a0 + a1) + (a2 + a3);
    if (hA == 0) p1 += tl * wAt + bA;
    p1 += __shfl_xor(p1, 1);
    if (hA == 0) h1g1[oA] = fast_tanh(p1);
    barrier_lds();                        // barrier 1

    // ---- stage B ----
    const float* srcB = h1g1 + ((oB < 64) ? 0 : 128) + qB * 32;
    float c0 = 0.f, c1 = 0.f, c2 = 0.f, c3 = 0.f;
#pragma unroll
    for (int g = 0; g < 8; g++) {
      float4 xv = *(const float4*)&srcB[g * 4];
      c0 += xv.x * wB[g * 4 + 0];
      c1 += xv.y * wB[g * 4 + 1];
      c2 += xv.z * wB[g * 4 + 2];
      c3 += xv.w * wB[g * 4 + 3];
    }
    float p2 = (c0 + c1) + (c2 + c3);
    p2 += __shfl_xor(p2, 1);
    p2 += __shfl_xor(p2, 2);
    if (qB == 0) {
      p2 += bB;
      if (oB < 64) {
        h2s[cB] = fast_tanh(p2);
      } else {
        gcs[cB] = fmaxf(p2, 0.f) + __logf(1.f + __expf(-fabsf(p2))) + mind;
      }
    }
    barrier_lds();                        // barrier 2

    // ---- stage C ----
    float d0 = 0.f, d1 = 0.f;
#pragma unroll
    for (int g = 0; g < 2; g++) {
      float4 hv = *(const float4*)&h2s[qC * 8 + g * 4];
      d0 += hv.x * wC[g * 4 + 0];
      d0 += hv.y * wC[g * 4 + 1];
      d1 += hv.z * wC[g * 4 + 2];
      d1 += hv.w * wC[g * 4 + 3];
    }
    float p3 = d0 + d1;
    p3 += __shfl_xor(p3, 1);
    p3 += __shfl_xor(p3, 2);
    p3 += __shfl_xor(p3, 4);
    if (qC == 0) {
      float dc = fminf(fmaxf(p3 + bC, -maxd), maxd);
      float yo = y_s[cC];
      float gg = gcs[cC] * fminf(fmaxf(yo, -10.f), 10.f);
      float yn = yo + dc * yo * hh + gg * nz * sq;
      yn = fminf(fmaxf(yn, 0.01f), 10.f);
      y_s[cC] = yn;
      out[(long)b * 32768 + (i + 1) * 64 + cC] = yn;
      outB[((long)b * 512 + i + 1) * 64 + cC] = f2b(yn);
    }
    nz = nzn;
    barrier_lds();                        // barrier 3
  }
}

// ---------------------------------------------------------------------------
__global__ __launch_bounds__(256) void prep_weights(
    const float* __restrict__ in_W, const float* __restrict__ Wq,
    const float* __restrict__ Wk, const float* __restrict__ Wv,
    const float* __restrict__ Wo, const float* __restrict__ fW1,
    const float* __restrict__ fW2,
    u16* __restrict__ inWt, u16* __restrict__ qkvWt, u16* __restrict__ Wot,
    u16* __restrict__ fW1t, u16* __restrict__ fW2t) {
  const int z = blockIdx.z, layer = blockIdx.y, tile = blockIdx.x;
  const float* src; u16* dst; int R, C, nl;
  switch (z) {
    case 0: src = in_W; dst = inWt; R = 64; C = 128; nl = 1; break;
    case 1: src = Wq + layer * 16384; dst = qkvWt + layer * 49152; R = 128; C = 128; nl = 4; break;
    case 2: src = Wk + layer * 16384; dst = qkvWt + layer * 49152 + 16384; R = 128; C = 128; nl = 4; break;
    case 3: src = Wv + layer * 16384; dst = qkvWt + layer * 49152 + 32768; R = 128; C = 128; nl = 4; break;
    case 4: src = Wo + layer * 16384; dst = Wot + layer * 16384; R = 128; C = 128; nl = 4; break;
    case 5: src = fW1 + layer * 65536; dst = fW1t + layer * 65536; R = 128; C = 512; nl = 4; break;
    default: src = fW2 + layer * 65536; dst = fW2t + layer * 65536; R = 512; C = 128; nl = 4; break;
  }
  const int nt = (R / 32) * (C / 32);
  if (layer >= nl || tile >= nt) return;
  const int tpr = C / 32;
  const int r0 = (tile / tpr) * 32, c0 = (tile % tpr) * 32;
  __shared__ float tl[32][33];
  const int tx = threadIdx.x & 31, ty = threadIdx.x >> 5;
#pragma unroll
  for (int p = 0; p < 4; p++)
    tl[ty + 8 * p][tx] = src[(long)(r0 + ty + 8 * p) * C + c0 + tx];
  __syncthreads();
#pragma unroll
  for (int p = 0; p < 4; p++)
    dst[(long)(c0 + ty + 8 * p) * R + r0 + tx] = f2b(tl[tx][ty + 8 * p]);
}

// ---------------------------------------------------------------------------
// bf16 MFMA GEMM. MODE 1: bf16+relu. MODE 3: bf16.
// ---------------------------------------------------------------------------
template <int MODE>
__global__ __launch_bounds__(256) void mfma_gemm(
    const u16* __restrict__ A, const u16* __restrict__ Bt,
    const float* __restrict__ bias, u16* __restrict__ outB, int K, int N) {
  __shared__ u16 As[128 * 40];
  __shared__ u16 Bs[64 * 40];
  const int t = threadIdx.x;
  const int nb = blockIdx.x * 64;
  const long mb = (long)blockIdx.y * 128;
  const int lane = t & 63, wave = t >> 6;
  const int wm = (wave >> 1) * 64, wn = (wave & 1) * 32;
  const int fr = lane & 15, quad = lane >> 4;

  f32x4 zero = {0.f, 0.f, 0.f, 0.f};
  f32x4 acc[4][2];
#pragma unroll
  for (int mi = 0; mi < 4; mi++)
#pragma unroll
    for (int ni = 0; ni < 2; ni++) acc[mi][ni] = zero;

  for (int k0 = 0; k0 < K; k0 += 32) {
#pragma unroll
    for (int p = 0; p < 2; p++) {
      int idx = t + p * 256, row = idx >> 2, seg = idx & 3;
      int4 v = *(const int4*)&A[(mb + row) * K + k0 + seg * 8];
      *(int4*)&As[row * 40 + seg * 8] = v;
    }
    {
      int row = t >> 2, seg = t & 3;
      int4 v = *(const int4*)&Bt[(long)(nb + row) * K + k0 + seg * 8];
      *(int4*)&Bs[row * 40 + seg * 8] = v;
    }
    __syncthreads();
    bf16x8 af[4], bfr[2];
#pragma unroll
    for (int mi = 0; mi < 4; mi++)
      af[mi] = *(const bf16x8*)&As[(wm + mi * 16 + fr) * 40 + quad * 8];
#pragma unroll
    for (int ni = 0; ni < 2; ni++)
      bfr[ni] = *(const bf16x8*)&Bs[(wn + ni * 16 + fr) * 40 + quad * 8];
#pragma unroll
    for (int mi = 0; mi < 4; mi++)
#pragma unroll
      for (int ni = 0; ni < 2; ni++)
        acc[mi][ni] = __builtin_amdgcn_mfma_f32_16x16x32_bf16(
            af[mi], bfr[ni], acc[mi][ni], 0, 0, 0);
    __syncthreads();
  }

#pragma unroll
  for (int mi = 0; mi < 4; mi++)
#pragma unroll
    for (int ni = 0; ni < 2; ni++) {
      int col = nb + wn + ni * 16 + fr;
      float bv = bias[col];
#pragma unroll
      for (int r = 0; r < 4; r++) {
        long row = mb + wm + mi * 16 + quad * 4 + r;
        float v = acc[mi][ni][r] + bv;
        if (MODE == 1) {
          outB[row * N + col] = f2b(fmaxf(v, 0.f));
        } else {
          outB[row * N + col] = f2b(v);
        }
      }
    }
}

// ---------------------------------------------------------------------------
// Fused GEMM + residual(bf16) + LayerNorm -> bf16. Tile 64x128, 512 blocks.
// ---------------------------------------------------------------------------
__global__ __launch_bounds__(256) void gemm_ln(
    const u16* __restrict__ A, const u16* __restrict__ Bt,
    const float* __restrict__ bias, const u16* __restrict__ resid,
    const float* __restrict__ gamma, const float* __restrict__ beta,
    u16* __restrict__ outB, int K) {
  __shared__ u16 As[64 * 40];
  __shared__ u16 Bs[128 * 40];
  __shared__ float s1[2][64], s2[2][64];
  const int t = threadIdx.x;
  const long mb = (long)blockIdx.x * 64;
  const int lane = t & 63, wave = t >> 6;
  const int wm = (wave >> 1) * 32, wn = (wave & 1) * 64;
  const int fr = lane & 15, quad = lane >> 4;

  f32x4 zero = {0.f, 0.f, 0.f, 0.f};
  f32x4 acc[2][4];
#pragma unroll
  for (int mi = 0; mi < 2; mi++)
#pragma unroll
    for (int ni = 0; ni < 4; ni++) acc[mi][ni] = zero;

  for (int k0 = 0; k0 < K; k0 += 32) {
    {
      int row = t >> 2, seg = t & 3;
      *(int4*)&As[row * 40 + seg * 8] =
          *(const int4*)&A[(mb + row) * K + k0 + seg * 8];
    }
#pragma unroll
    for (int p = 0; p < 2; p++) {
      int idx = t + p * 256, row = idx >> 2, seg = idx & 3;
      *(int4*)&Bs[row * 40 + seg * 8] =
          *(const int4*)&Bt[(long)row * K + k0 + seg * 8];
    }
    __syncthreads();
    bf16x8 af[2], bfr[4];
#pragma unroll
    for (int mi = 0; mi < 2; mi++)
      af[mi] = *(const bf16x8*)&As[(wm + mi * 16 + fr) * 40 + quad * 8];
#pragma unroll
    for (int ni = 0; ni < 4; ni++)
      bfr[ni] = *(const bf16x8*)&Bs[(wn + ni * 16 + fr) * 40 + quad * 8];
#pragma unroll
    for (int mi = 0; mi < 2; mi++)
#pragma unroll
      for (int ni = 0; ni < 4; ni++)
        acc[mi][ni] = __builtin_amdgcn_mfma_f32_16x16x32_bf16(
            af[mi], bfr[ni], acc[mi][ni], 0, 0, 0);
    __syncthreads();
  }

  float bv[4], gv[4], be[4];
#pragma unroll
  for (int ni = 0; ni < 4; ni++) {
    int col = wn + ni * 16 + fr;
    bv[ni] = bias[col];
    gv[ni] = gamma[col];
    be[ni] = beta[col];
  }

#pragma unroll
  for (int mi = 0; mi < 2; mi++) {
#pragma unroll
    for (int r = 0; r < 4; r++) {
      int rloc = wm + mi * 16 + quad * 4 + r;
      long row = mb + rloc;
      float s = 0.f, ss = 0.f;
#pragma unroll
      for (int ni = 0; ni < 4; ni++) {
        int col = wn + ni * 16 + fr;
        float v = acc[mi][ni][r] + bv[ni] + b2f(resid[row * DD + col]);
        acc[mi][ni][r] = v;
        s += v;
        ss += v * v;
      }
      s += __shfl_xor(s, 1); ss += __shfl_xor(ss, 1);
      s += __shfl_xor(s, 2); ss += __shfl_xor(ss, 2);
      s += __shfl_xor(s, 4); ss += __shfl_xor(ss, 4);
      s += __shfl_xor(s, 8); ss += __shfl_xor(ss, 8);
      if (fr == 0) {
        s1[wn >> 6][rloc] = s;
        s2[wn >> 6][rloc] = ss;
      }
    }
  }
  __syncthreads();

#pragma unroll
  for (int mi = 0; mi < 2; mi++) {
#pragma unroll
    for (int r = 0; r < 4; r++) {
      int rloc = wm + mi * 16 + quad * 4 + r;
      long row = mb + rloc;
      float sum = s1[0][rloc] + s1[1][rloc];
      float sumsq = s2[0][rloc] + s2[1][rloc];
      float mean = sum * (1.f / 128.f);
      float var = sumsq * (1.f / 128.f) - mean * mean;
      float rstd = rsqrtf(var + 1e-5f);
#pragma unroll
      for (int ni = 0; ni < 4; ni++) {
        int col = wn + ni * 16 + fr;
        float o = (acc[mi][ni][r] - mean) * rstd * gv[ni] + be[ni];
        outB[row * DD + col] = f2b(o);
      }
    }
  }
}

// ---------------------------------------------------------------------------
// Fused QKV-projection + flash attention. One block per (b,h), 512 blocks,
// 2 blocks/CU (64.3 KB LDS). Block computes its head's Q/K/V (512x16 each,
// K=128 — head slices exactly partition the QKV GEMM) into LDS, then runs
// the S^T-orientation online-softmax loop (verified round 8).
// ---------------------------------------------------------------------------
__global__ __launch_bounds__(256, 2) void qkv_attn(
    const u16* __restrict__ xb, const u16* __restrict__ qkvW,
    const float* __restrict__ bq, const float* __restrict__ bk,
    const float* __restrict__ bv, u16* __restrict__ Og) {
  const int bh = blockIdx.x;
  const int b = bh >> 3, h = bh & 7;
  __shared__ u16 Ks[512 * 24];     // [key][d]  (24 KB)
  __shared__ u16 Vt[16 * 520];     // [d][key]  (16.3 KB)
  __shared__ u16 Qs[512 * 24];     // [q][d]    (24 KB)
  const int t = threadIdx.x;
  const int w = t >> 6, lane = t & 63;
  const int fr = lane & 15, quad = lane >> 4;
  const long obase = ((long)b * SS) * DD + h * 16;
  const u16* xrow = xb + (long)b * SS * DD;

  // ---- head weight B-frags (register-resident) ----
  const u16* Wq_h = qkvW + (h * 16) * 128;
  const u16* Wk_h = qkvW + 16384 + (h * 16) * 128;
  const u16* Wv_h = qkvW + 32768 + (h * 16) * 128;
  bf16x8 wqf[4], wkf[4], wvf[4];
#pragma unroll
  for (int c = 0; c < 4; c++) {
    wqf[c] = *(const bf16x8*)&Wq_h[fr * 128 + c * 32 + quad * 8];
    wkf[c] = *(const bf16x8*)&Wk_h[fr * 128 + c * 32 + quad * 8];
    wvf[c] = *(const bf16x8*)&Wv_h[fr * 128 + c * 32 + quad * 8];
  }
  const float bqv = bq[h * 16 + fr];
  const float bkv = bk[h * 16 + fr];
  const float bvv = bv[h * 16 + fr];
  const f32x4 z4 = {0.f, 0.f, 0.f, 0.f};

  // ---- project Q/K/V for this head into LDS ----
  for (int tile = w; tile < 32; tile += 4) {
    const int t0 = tile * 16;
    bf16x8 af[4];
#pragma unroll
    for (int c = 0; c < 4; c++)
      af[c] = *(const bf16x8*)&xrow[(t0 + fr) * 128 + c * 32 + quad * 8];
    f32x4 qa = z4, ka = z4, va = z4;
#pragma unroll
    for (int c = 0; c < 4; c++) {
      qa = __builtin_amdgcn_mfma_f32_16x16x32_bf16(af[c], wqf[c], qa, 0, 0, 0);
      ka = __builtin_amdgcn_mfma_f32_16x16x32_bf16(af[c], wkf[c], ka, 0, 0, 0);
      va = __builtin_amdgcn_mfma_f32_16x16x32_bf16(af[c], wvf[c], va, 0, 0, 0);
    }
    // C-layout: lane holds (d = fr, row = t0 + quad*4 + r)
#pragma unroll
    for (int r = 0; r < 4; r++) {
      int row = t0 + quad * 4 + r;
      Qs[row * 24 + fr] = f2b(qa[r] + bqv);
      Ks[row * 24 + fr] = f2b(ka[r] + bkv);
      Vt[fr * 520 + row] = f2b(va[r] + bvv);
    }
  }
  __syncthreads();

  // ---- flash attention (S^T orientation) ----
  const float scale = 0.25f;                 // 1/sqrt(16)
  const int addrA = (((quad & 1) * 32) + fr) * 4;
  const int addrB = addrA + 64;
  const bool loTile = (quad < 2);

  for (int qt = w; qt < 32; qt += 4) {
    const int q0 = qt * 16;
    bf16x8 qf = {0, 0, 0, 0, 0, 0, 0, 0};
    if (quad < 2)
      qf = *(const bf16x8*)&Qs[(q0 + fr) * 24 + quad * 8];
    f32x4 oacc = {0.f, 0.f, 0.f, 0.f};
    float mrun = -1e30f, lrun = 0.f;

    for (int kt = 0; kt < 16; kt++) {
      const int k0 = kt * 32;
      bf16x8 kf0 = {0, 0, 0, 0, 0, 0, 0, 0};
      bf16x8 kf1 = {0, 0, 0, 0, 0, 0, 0, 0};
      if (quad < 2) {
        kf0 = *(const bf16x8*)&Ks[(k0 + fr) * 24 + quad * 8];
        kf1 = *(const bf16x8*)&Ks[(k0 + 16 + fr) * 24 + quad * 8];
      }
      f32x4 slo = __builtin_amdgcn_mfma_f32_16x16x32_bf16(kf0, qf, z4, 0, 0, 0);
      f32x4 shi = __builtin_amdgcn_mfma_f32_16x16x32_bf16(kf1, qf, z4, 0, 0, 0);
      float s[8];
#pragma unroll
      for (int r = 0; r < 4; r++) {
        s[r] = slo[r] * scale;
        s[4 + r] = shi[r] * scale;
      }
      float mx = s[0];
#pragma unroll
      for (int r = 1; r < 8; r++) mx = fmaxf(mx, s[r]);
      mx = fmaxf(mx, __shfl_xor(mx, 16));
      mx = fmaxf(mx, __shfl_xor(mx, 32));
      float nm = fmaxf(mrun, mx);
      float alpha = __expf(mrun - nm);
      mrun = nm;
      float p[8], rs = 0.f;
#pragma unroll
      for (int r = 0; r < 8; r++) {
        p[r] = __expf(s[r] - nm);
        rs += p[r];
      }
      rs += __shfl_xor(rs, 16);
      rs += __shfl_xor(rs, 32);
      lrun = lrun * alpha + rs;
#pragma unroll
      for (int r = 0; r < 4; r++) oacc[r] *= alpha;

      int pk0 = ((int)f2b(p[1]) << 16) | f2b(p[0]);
      int pk1 = ((int)f2b(p[3]) << 16) | f2b(p[2]);
      int pk2 = ((int)f2b(p[5]) << 16) | f2b(p[4]);
      int pk3 = ((int)f2b(p[7]) << 16) | f2b(p[6]);
      int B0a = __builtin_amdgcn_ds_bpermute(addrA, pk0);
      int B0b = __builtin_amdgcn_ds_bpermute(addrA, pk2);
      int B1a = __builtin_amdgcn_ds_bpermute(addrA, pk1);
      int B1b = __builtin_amdgcn_ds_bpermute(addrA, pk3);
      int B2a = __builtin_amdgcn_ds_bpermute(addrB, pk0);
      int B2b = __builtin_amdgcn_ds_bpermute(addrB, pk2);
      int B3a = __builtin_amdgcn_ds_bpermute(addrB, pk1);
      int B3b = __builtin_amdgcn_ds_bpermute(addrB, pk3);
      union { int i[4]; bf16x8 v; } pu;
      pu.i[0] = loTile ? B0a : B0b;
      pu.i[1] = loTile ? B1a : B1b;
      pu.i[2] = loTile ? B2a : B2b;
      pu.i[3] = loTile ? B3a : B3b;
      bf16x8 vf = *(const bf16x8*)&Vt[fr * 520 + k0 + quad * 8];
      oacc = __builtin_amdgcn_mfma_f32_16x16x32_bf16(vf, pu.v, oacc, 0, 0, 0);
    }

    float inv = __fdividef(1.f, lrun);
    ushort4 o;
    o.x = f2b(oacc[0] * inv);
    o.y = f2b(oacc[1] * inv);
    o.z = f2b(oacc[2] * inv);
    o.w = f2b(oacc[3] * inv);
    *(ushort4*)&Og[obase + (long)(q0 + fr) * DD + quad * 4] = o;
  }
}

// ---------------------------------------------------------------------------
__global__ __launch_bounds__(128) void pool_kernel(const u16* __restrict__ X,
                                                   float* __restrict__ P) {
  const int b = blockIdx.x, c = threadIdx.x;
  float acc = 0.f;
  for (int s = 0; s < SS; s++) acc += b2f(X[((long)b * SS + s) * DD + c]);
  P[b * DD + c] = acc * (1.f / 512.f);
}

__global__ __launch_bounds__(64) void cls_kernel(
    const float* __restrict__ P, const float* __restrict__ W1,
    const float* __restrict__ b1, const float* __restrict__ W2,
    const float* __restrict__ b2, float* __restrict__ L) {
  const int b = blockIdx.x, t = threadIdx.x;
  __shared__ float sp[128];
  __shared__ float sh[64];
  sp[t] = P[b * DD + t];
  sp[t + 64] = P[b * DD + 64 + t];
  __syncthreads();
  float acc = b1[t];
  for (int k = 0; k < 128; k++) acc += sp[k] * W1[k * 64 + t];
  sh[t] = fmaxf(acc, 0.f);
  __syncthreads();
  if (t < 5) {
    float acc2 = b2[t];
    for (int k = 0; k < 64; k++) acc2 += sh[k] * W2[k * 5 + t];
    L[b * 5 + t] = acc2;
  }
}

// ---------------------------------------------------------------------------
extern "C" void kernel_launch(void* const* d_in, const int* in_sizes, int n_in,
                              void* d_out, int out_size, void* d_ws, size_t ws_size,
                              hipStream_t stream) {
  const float* ts    = (const float*)d_in[0];
  const float* noise = (const float*)d_in[2];
  const float* dW1   = (const float*)d_in[3];
  const float* db1   = (const float*)d_in[4];
  const float* dW2   = (const float*)d_in[5];
  const float* db2   = (const float*)d_in[6];
  const float* dW3   = (const float*)d_in[7];
  const float* db3   = (const float*)d_in[8];
  const float* gW1   = (const float*)d_in[9];
  const float* gb1   = (const float*)d_in[10];
  const float* gW2   = (const float*)d_in[11];
  const float* gb2   = (const float*)d_in[12];
  const float* mind  = (const float*)d_in[13];
  const float* maxd  = (const float*)d_in[14];
  const float* in_W  = (const float*)d_in[15];
  const float* in_b  = (const float*)d_in[16];
  const float* Wq    = (const float*)d_in[17];
  const float* bq    = (const float*)d_in[18];
  const float* Wk    = (const float*)d_in[19];
  const float* bk    = (const float*)d_in[20];
  const float* Wv    = (const float*)d_in[21];
  const float* bv    = (const float*)d_in[22];
  const float* Wo    = (const float*)d_in[23];
  const float* bo    = (const float*)d_in[24];
  const float* ln1s  = (const float*)d_in[25];
  const float* ln1b  = (const float*)d_in[26];
  const float* fW1   = (const float*)d_in[27];
  const float* fb1   = (const float*)d_in[28];
  const float* fW2   = (const float*)d_in[29];
  const float* fb2   = (const float*)d_in[30];
  const float* ln2s  = (const float*)d_in[31];
  const float* ln2b  = (const float*)d_in[32];
  const float* cW1   = (const float*)d_in[33];
  const float* cb1   = (const float*)d_in[34];
  const float* cW2   = (const float*)d_in[35];
  const float* cb2   = (const float*)d_in[36];

  float* logits = (float*)d_out;
  float* sde    = logits + BB * 5;

  // Workspace (all-bf16 residual stream):
  char* W = (char*)d_ws;
  u16*  bxb    = (u16*)(W);                   //  8 MB bf16 x
  u16*  bh     = (u16*)(W + (8u << 20));      // 32 MB FFN hidden
  u16*  bob    = (u16*)(W + (40u << 20));     //  8 MB bf16 attn out
  u16*  bsb    = (u16*)(W + (48u << 20));     //  4 MB bf16 sde feats
  u16*  wts    = (u16*)(W + (52u << 20));     // ~1.5 MB bf16 weights
  float* bp    = (float*)(W + (54u << 20));   // pooled 64x128

  u16* inWt  = wts;                 // [128][64]
  u16* qkvWt = inWt + 8192;         // [4][3][128][128]
  u16* Wot   = qkvWt + 196608;      // [4][128][128]
  u16* fW1t  = Wot + 65536;         // [4][512][128]
  u16* fW2t  = fW1t + 262144;       // [4][128][512]

  prep_weights<<<dim3(64, 4, 7), 256, 0, stream>>>(in_W, Wq, Wk, Wv, Wo, fW1, fW2,
                                                   inWt, qkvWt, Wot, fW1t, fW2t);

  sde_kernel<<<64, 512, 0, stream>>>(ts, noise, dW1, db1, dW2, db2, dW3, db3,
                                     gW1, gb1, gW2, gb2, mind, maxd, sde, bsb);

  // x = sde @ in_W + in_b  (bf16)
  mfma_gemm<3><<<dim3(2, 256), 256, 0, stream>>>(bsb, inWt, in_b, bxb, 64, 128);

  for (int l = 0; l < 4; l++) {
    qkv_attn<<<BB * NHD, 256, 0, stream>>>(bxb, qkvWt + l * 49152,
                                           bq + l * DD, bk + l * DD, bv + l * DD,
                                           bob);
    gemm_ln<<<512, 256, 0, stream>>>(bob, Wot + l * 16384, bo + l * DD, bxb,
                                     ln1s + l * DD, ln1b + l * DD, bxb, 128);
    mfma_gemm<1><<<dim3(8, 256), 256, 0, stream>>>(bxb, fW1t + l * 65536,
                                                   fb1 + l * 512, bh, 128, 512);
    gemm_ln<<<512, 256, 0, stream>>>(bh, fW2t + l * 65536, fb2 + l * DD, bxb,
                                     ln2s + l * DD, ln2b + l * DD, bxb, 512);
  }

  pool_kernel<<<BB, 128, 0, stream>>>(bxb, bp);
  cls_kernel<<<BB, 64, 0, stream>>>(bp, cW1, cb1, cW2, cb2, logits);
}